// Round 1
// baseline (463.332 us; speedup 1.0000x reference)
//
#include <hip/hip_runtime.h>
#include <hip/hip_bf16.h>
#include <stdint.h>
#include <math.h>

typedef short short8 __attribute__((ext_vector_type(8)));
typedef float f32x4 __attribute__((ext_vector_type(4)));
typedef unsigned short u16;

__device__ __forceinline__ u16 f2bf(float f) {
    unsigned u = __float_as_uint(f);
    unsigned r = 0x7FFFu + ((u >> 16) & 1u);
    return (u16)((u + r) >> 16);
}

#define GL_LDS16(g, l)                                                         \
    __builtin_amdgcn_global_load_lds(                                          \
        (const __attribute__((address_space(1))) void*)(g),                    \
        (__attribute__((address_space(3))) void*)(l), 16, 0, 0)

// ---------------- elementwise f32 -> bf16 convert (8 elems/thread) ----------
__global__ __launch_bounds__(256) void k_convert(const float* __restrict__ src,
                                                 u16* __restrict__ dst, int n8) {
    int i = blockIdx.x * 256 + threadIdx.x;
    if (i >= n8) return;
    const float4* s = (const float4*)src + (size_t)i * 2;
    float4 a = s[0], b = s[1];
    uint4 o;
    o.x = (unsigned)f2bf(a.x) | ((unsigned)f2bf(a.y) << 16);
    o.y = (unsigned)f2bf(a.z) | ((unsigned)f2bf(a.w) << 16);
    o.z = (unsigned)f2bf(b.x) | ((unsigned)f2bf(b.y) << 16);
    o.w = (unsigned)f2bf(b.z) | ((unsigned)f2bf(b.w) << 16);
    ((uint4*)dst)[i] = o;
}

// ---------------- transpose + convert: W[K][N] f32 -> WT[N][K] bf16 ---------
__global__ __launch_bounds__(256) void k_transpose(const float* __restrict__ W,
                                                   u16* __restrict__ WT, int Dim) {
    __shared__ float tile[64][65];
    int k0 = blockIdx.x * 64, n0 = blockIdx.y * 64;
    int t = threadIdx.x;
    int col = t & 63, rb = t >> 6;  // 4 rows per pass
#pragma unroll
    for (int i = 0; i < 16; ++i) {
        int r = i * 4 + rb;
        tile[r][col] = W[(size_t)(k0 + r) * Dim + n0 + col];
    }
    __syncthreads();
#pragma unroll
    for (int i = 0; i < 16; ++i) {
        int r = i * 4 + rb;
        WT[(size_t)(n0 + r) * Dim + k0 + col] = f2bf(tile[col][r]);
    }
}

// ---------------- bf16 MFMA GEMM: C[M,N] = A[M,K] @ BT[N,K]^T + bias --------
// 128x128 tile, BK=32, 256 threads = 4 waves (2x2 of 64x64 sub-tiles)
__global__ __launch_bounds__(256) void k_gemm(const u16* __restrict__ A,
                                              const u16* __restrict__ BT,
                                              const float* __restrict__ bias,
                                              float* __restrict__ C,
                                              int M, int N, int K) {
    __shared__ __align__(16) u16 As[128 * 32];
    __shared__ __align__(16) u16 Bs[128 * 32];
    const int t = threadIdx.x;
    const int lane = t & 63;
    const int wave = t >> 6;
    const int wr = wave >> 1, wc = wave & 1;
    const int m0 = blockIdx.y * 128, n0 = blockIdx.x * 128;
    const int r16 = lane & 15, kq = lane >> 4;

    f32x4 acc[4][4];
#pragma unroll
    for (int m = 0; m < 4; ++m)
#pragma unroll
        for (int n = 0; n < 4; ++n) acc[m][n] = (f32x4){0.f, 0.f, 0.f, 0.f};

    for (int kt = 0; kt < K; kt += 32) {
        // stage A tile [128][32] and B tile [128 n][32 k] via async DMA
#pragma unroll
        for (int i = 0; i < 2; ++i) {
            int q = i * 256 + t;
            int row = q >> 2, c = (q & 3) << 3;
            GL_LDS16(A + (size_t)(m0 + row) * K + kt + c, &As[(q & ~63) * 8]);
            GL_LDS16(BT + (size_t)(n0 + row) * K + kt + c, &Bs[(q & ~63) * 8]);
        }
        __syncthreads();  // drains vmcnt: LDS tiles complete

        short8 a[4], b[4];
#pragma unroll
        for (int m = 0; m < 4; ++m)
            a[m] = *(const short8*)&As[(wr * 64 + m * 16 + r16) * 32 + kq * 8];
#pragma unroll
        for (int n = 0; n < 4; ++n)
            b[n] = *(const short8*)&Bs[(wc * 64 + n * 16 + r16) * 32 + kq * 8];
#pragma unroll
        for (int m = 0; m < 4; ++m)
#pragma unroll
            for (int n = 0; n < 4; ++n)
                acc[m][n] = __builtin_amdgcn_mfma_f32_16x16x32_bf16(a[m], b[n],
                                                                    acc[m][n], 0, 0, 0);
        __syncthreads();  // protect LDS before next stage
    }

    // epilogue: D row=(lane>>4)*4+reg, col=lane&15  [verified m89/m91]
#pragma unroll
    for (int n = 0; n < 4; ++n) {
        int col = n0 + wc * 64 + n * 16 + r16;
        float bv = bias[col];
#pragma unroll
        for (int m = 0; m < 4; ++m) {
            int row = m0 + wr * 64 + m * 16 + kq * 4;
#pragma unroll
            for (int j = 0; j < 4; ++j)
                C[(size_t)(row + j) * N + col] = acc[m][n][j] + bv;
        }
    }
}

// ---------------- diagonal-softmax + weighted=d*V (bf16 out) ----------------
// grid (S/64, H, B), 256 threads; quad (4 lanes) per row; K staged in LDS.
__global__ __launch_bounds__(256) void k_scores(const float* __restrict__ Q,
                                                const float* __restrict__ Kmat,
                                                const float* __restrict__ V,
                                                const int* __restrict__ lengths,
                                                u16* __restrict__ Wt,
                                                int S, int D) {
    __shared__ __align__(16) float Ks[64 * 64];
    const int t = threadIdx.x;
    const int b = blockIdx.z, h = blockIdx.y, s0 = blockIdx.x * 64;
    const int r = t >> 2, sub = t & 3;
    const int s = s0 + r;
    const int len = lengths[b];
    const size_t rowOff = ((size_t)(b * S) + s) * D + h * 64 + sub * 16;

    const float4* qp = (const float4*)(Q + rowOff);
    float4 q0 = qp[0], q1 = qp[1], q2 = qp[2], q3 = qp[3];

    float mrun = -INFINITY, sum = 0.f, diag = 0.f;
    const int jmax_row = (s < len) ? s : -1;          // causal + pad combined
    const int jmax_blk = min(s0 + 63, len - 1);       // block-level key bound

    for (int j0 = 0; j0 <= jmax_blk; j0 += 64) {
        __syncthreads();
        // stage K tile [64 rows][64 dk] f32
#pragma unroll
        for (int i = 0; i < 4; ++i) {
            int qd = i * 256 + t;
            int row = qd >> 4, c4 = (qd & 15) << 2;
            *(float4*)&Ks[row * 64 + c4] =
                *(const float4*)(Kmat + ((size_t)(b * S) + j0 + row) * D + h * 64 + c4);
        }
        __syncthreads();
        const int jn = min(64, jmax_blk - j0 + 1);
        for (int j = 0; j < jn; ++j) {
            const float4* kr = (const float4*)&Ks[j * 64 + sub * 16];
            float4 ka = kr[0], kb = kr[1], kc = kr[2], kd = kr[3];
            float p;
            p = q0.x * ka.x + q0.y * ka.y + q0.z * ka.z + q0.w * ka.w;
            p += q1.x * kb.x + q1.y * kb.y + q1.z * kb.z + q1.w * kb.w;
            p += q2.x * kc.x + q2.y * kc.y + q2.z * kc.z + q2.w * kc.w;
            p += q3.x * kd.x + q3.y * kd.y + q3.z * kd.z + q3.w * kd.w;
            p += __shfl_xor(p, 1);
            p += __shfl_xor(p, 2);  // all 4 lanes of quad now hold full dot
            const int jj = j0 + j;
            if (jj <= jmax_row) {
                float nm = fmaxf(mrun, p);
                sum = sum * __expf(mrun - nm) + __expf(p - nm);
                mrun = nm;
                if (jj == s) diag = p;
            }
        }
    }
    const float d = (jmax_row >= 0) ? __expf(diag - mrun) / sum : 0.f;

    const float4* vp = (const float4*)(V + rowOff);
    float4 v0 = vp[0], v1 = vp[1], v2 = vp[2], v3 = vp[3];
    uint4 o0, o1;
    o0.x = (unsigned)f2bf(v0.x * d) | ((unsigned)f2bf(v0.y * d) << 16);
    o0.y = (unsigned)f2bf(v0.z * d) | ((unsigned)f2bf(v0.w * d) << 16);
    o0.z = (unsigned)f2bf(v1.x * d) | ((unsigned)f2bf(v1.y * d) << 16);
    o0.w = (unsigned)f2bf(v1.z * d) | ((unsigned)f2bf(v1.w * d) << 16);
    o1.x = (unsigned)f2bf(v2.x * d) | ((unsigned)f2bf(v2.y * d) << 16);
    o1.y = (unsigned)f2bf(v2.z * d) | ((unsigned)f2bf(v2.w * d) << 16);
    o1.z = (unsigned)f2bf(v3.x * d) | ((unsigned)f2bf(v3.y * d) << 16);
    o1.w = (unsigned)f2bf(v3.z * d) | ((unsigned)f2bf(v3.w * d) << 16);
    uint4* wp = (uint4*)(Wt + rowOff);
    wp[0] = o0;
    wp[1] = o1;
}

extern "C" void kernel_launch(void* const* d_in, const int* in_sizes, int n_in,
                              void* d_out, int out_size, void* d_ws, size_t ws_size,
                              hipStream_t stream) {
    const float* batch = (const float*)d_in[0];
    const int* lengths = (const int*)d_in[1];
    const float* wq = (const float*)d_in[2];
    const float* bq = (const float*)d_in[3];
    const float* wk = (const float*)d_in[4];
    const float* bk = (const float*)d_in[5];
    const float* wv = (const float*)d_in[6];
    const float* bv = (const float*)d_in[7];
    const float* w0 = (const float*)d_in[8];
    const float* b0 = (const float*)d_in[9];

    const int D = in_sizes[3];               // 1024
    const int B = in_sizes[1];               // 8
    const int S = in_sizes[0] / (B * D);     // 1024
    const int H = 16;
    const int M = B * S;                     // 8192

    char* ws = (char*)d_ws;
    u16* Ab = (u16*)ws;            ws += (size_t)M * D * 2;
    u16* wqT = (u16*)ws;           ws += (size_t)D * D * 2;
    u16* wkT = (u16*)ws;           ws += (size_t)D * D * 2;
    u16* wvT = (u16*)ws;           ws += (size_t)D * D * 2;
    u16* w0T = (u16*)ws;           ws += (size_t)D * D * 2;
    float* Qf = (float*)ws;        ws += (size_t)M * D * 4;
    float* Kf = (float*)ws;        ws += (size_t)M * D * 4;
    float* Vf = (float*)ws;        ws += (size_t)M * D * 4;
    u16* Wtb = (u16*)ws;           ws += (size_t)M * D * 2;

    // 1. converts
    k_convert<<<(M * D / 8 + 255) / 256, 256, 0, stream>>>(batch, Ab, M * D / 8);
    dim3 tg(D / 64, D / 64);
    k_transpose<<<tg, 256, 0, stream>>>(wq, wqT, D);
    k_transpose<<<tg, 256, 0, stream>>>(wk, wkT, D);
    k_transpose<<<tg, 256, 0, stream>>>(wv, wvT, D);
    k_transpose<<<tg, 256, 0, stream>>>(w0, w0T, D);

    // 2. Q/K/V projections (f32 out)
    dim3 gg(D / 128, M / 128);
    k_gemm<<<gg, 256, 0, stream>>>(Ab, wqT, bq, Qf, M, D, D);
    k_gemm<<<gg, 256, 0, stream>>>(Ab, wkT, bk, Kf, M, D, D);
    k_gemm<<<gg, 256, 0, stream>>>(Ab, wvT, bv, Vf, M, D, D);

    // 3. diagonal softmax + weighted = d*V (bf16)
    dim3 sg(S / 64, H, B);
    k_scores<<<sg, 256, 0, stream>>>(Qf, Kf, Vf, lengths, Wtb, S, D);

    // 4. output projection -> d_out (f32)
    k_gemm<<<gg, 256, 0, stream>>>(Wtb, w0T, b0, (float*)d_out, M, D, D);
}

// Round 2
// 201.643 us; speedup vs baseline: 2.2978x; 2.2978x over previous
//
#include <hip/hip_runtime.h>
#include <hip/hip_bf16.h>
#include <stdint.h>
#include <math.h>

typedef short short8 __attribute__((ext_vector_type(8)));
typedef float f32x4 __attribute__((ext_vector_type(4)));
typedef unsigned short u16;

__device__ __forceinline__ u16 f2bf(float f) {
    unsigned u = __float_as_uint(f);
    unsigned r = 0x7FFFu + ((u >> 16) & 1u);
    return (u16)((u + r) >> 16);
}

#define GL_LDS16(g, l)                                                         \
    __builtin_amdgcn_global_load_lds(                                          \
        (const __attribute__((address_space(1))) void*)(g),                    \
        (__attribute__((address_space(3))) void*)(l), 16, 0, 0)

// ---------------- elementwise f32 -> bf16 convert (8 elems/thread) ----------
__global__ __launch_bounds__(256) void k_convert(const float* __restrict__ src,
                                                 u16* __restrict__ dst, int n8) {
    int i = blockIdx.x * 256 + threadIdx.x;
    if (i >= n8) return;
    const float4* s = (const float4*)src + (size_t)i * 2;
    float4 a = s[0], b = s[1];
    uint4 o;
    o.x = (unsigned)f2bf(a.x) | ((unsigned)f2bf(a.y) << 16);
    o.y = (unsigned)f2bf(a.z) | ((unsigned)f2bf(a.w) << 16);
    o.z = (unsigned)f2bf(b.x) | ((unsigned)f2bf(b.y) << 16);
    o.w = (unsigned)f2bf(b.z) | ((unsigned)f2bf(b.w) << 16);
    ((uint4*)dst)[i] = o;
}

// ---------------- transpose + convert: W[K][N] f32 -> WT[N][K] bf16 ---------
__global__ __launch_bounds__(256) void k_transpose(const float* __restrict__ W,
                                                   u16* __restrict__ WT, int Dim) {
    __shared__ float tile[64][65];
    int k0 = blockIdx.x * 64, n0 = blockIdx.y * 64;
    int t = threadIdx.x;
    int col = t & 63, rb = t >> 6;
#pragma unroll
    for (int i = 0; i < 16; ++i) {
        int r = i * 4 + rb;
        tile[r][col] = W[(size_t)(k0 + r) * Dim + n0 + col];
    }
    __syncthreads();
#pragma unroll
    for (int i = 0; i < 16; ++i) {
        int r = i * 4 + rb;
        WT[(size_t)(n0 + r) * Dim + k0 + col] = f2bf(tile[col][r]);
    }
}

// ---------------- bf16 MFMA GEMM: C[M,N] = A[M,K] @ BT[N,K]^T + bias --------
// MODE 0: f32 out.  MODE 1: hi/lo bf16 split out (for Q/K).
template <int MODE>
__global__ __launch_bounds__(256) void k_gemm(const u16* __restrict__ A,
                                              const u16* __restrict__ BT,
                                              const float* __restrict__ bias,
                                              float* __restrict__ C,
                                              u16* __restrict__ Ohi,
                                              u16* __restrict__ Olo,
                                              int M, int N, int K) {
    __shared__ __align__(16) u16 As[128 * 32];
    __shared__ __align__(16) u16 Bs[128 * 32];
    const int t = threadIdx.x;
    const int lane = t & 63;
    const int wave = t >> 6;
    const int wr = wave >> 1, wc = wave & 1;
    const int m0 = blockIdx.y * 128, n0 = blockIdx.x * 128;
    const int r16 = lane & 15, kq = lane >> 4;

    f32x4 acc[4][4];
#pragma unroll
    for (int m = 0; m < 4; ++m)
#pragma unroll
        for (int n = 0; n < 4; ++n) acc[m][n] = (f32x4){0.f, 0.f, 0.f, 0.f};

    for (int kt = 0; kt < K; kt += 32) {
#pragma unroll
        for (int i = 0; i < 2; ++i) {
            int q = i * 256 + t;
            int row = q >> 2, c = (q & 3) << 3;
            GL_LDS16(A + (size_t)(m0 + row) * K + kt + c, &As[(q & ~63) * 8]);
            GL_LDS16(BT + (size_t)(n0 + row) * K + kt + c, &Bs[(q & ~63) * 8]);
        }
        __syncthreads();

        short8 a[4], bfr[4];
#pragma unroll
        for (int m = 0; m < 4; ++m)
            a[m] = *(const short8*)&As[(wr * 64 + m * 16 + r16) * 32 + kq * 8];
#pragma unroll
        for (int n = 0; n < 4; ++n)
            bfr[n] = *(const short8*)&Bs[(wc * 64 + n * 16 + r16) * 32 + kq * 8];
#pragma unroll
        for (int m = 0; m < 4; ++m)
#pragma unroll
            for (int n = 0; n < 4; ++n)
                acc[m][n] = __builtin_amdgcn_mfma_f32_16x16x32_bf16(a[m], bfr[n],
                                                                    acc[m][n], 0, 0, 0);
        __syncthreads();
    }

#pragma unroll
    for (int n = 0; n < 4; ++n) {
        int col = n0 + wc * 64 + n * 16 + r16;
        float bv = bias[col];
#pragma unroll
        for (int m = 0; m < 4; ++m) {
            int row = m0 + wr * 64 + m * 16 + kq * 4;
#pragma unroll
            for (int j = 0; j < 4; ++j) {
                float val = acc[m][n][j] + bv;
                size_t idx = (size_t)(row + j) * N + col;
                if (MODE == 0) {
                    C[idx] = val;
                } else {
                    u16 hi = f2bf(val);
                    float hf = __uint_as_float((unsigned)hi << 16);
                    Ohi[idx] = hi;
                    Olo[idx] = f2bf(val - hf);
                }
            }
        }
    }
}

// ---------------- MFMA diagonal-softmax + weighted = d*V --------------------
// 1D grid of (S/256)*H*B blocks, 256 threads = 4 waves.
// Block pairs row-chunk bx (128 rows) with chunk (nchunk-1-bx) -> uniform work.
// Wave w handles rows qb[m] + w*16 .. +15 for m=0..3 (interleaved).
__global__ __launch_bounds__(256, 2) void k_scores(
    const u16* __restrict__ Qhi, const u16* __restrict__ Qlo,
    const u16* __restrict__ Khi, const u16* __restrict__ Klo,
    const float* __restrict__ V, const int* __restrict__ lengths,
    u16* __restrict__ Wt, int S, int D, int nchunk) {
    __shared__ __align__(16) u16 KsHi[64 * 64];
    __shared__ __align__(16) u16 KsLo[64 * 64];
    __shared__ float dbuf[256];

    // XCD-chunked bijective remap (nwg % 8 == 0): co-locate a (b,h)'s blocks
    const int nwg = gridDim.x;
    const int qch = nwg >> 3;
    const int wg = blockIdx.x;
    const int id = (wg & 7) * qch + (wg >> 3);
    const int npair = nchunk >> 1;
    const int bx = id % npair;
    const int h = (id / npair) & 15;
    const int b = id / (npair * 16);

    const int a0 = bx * 128;
    const int b0 = (nchunk - 1 - bx) * 128;
    const int t = threadIdx.x;
    const int lane = t & 63, wave = t >> 6;
    const int r16 = lane & 15, h2 = lane >> 4;
    const int len = lengths[b];

    // Q fragments (hi+lo), rows qb[m] + wave*16 + r16, k = ks*32 + h2*8
    short8 qh[4][2], ql[4][2];
#pragma unroll
    for (int m = 0; m < 4; ++m) {
        const int qm = (m < 2) ? a0 + (m << 6) : b0 + ((m - 2) << 6);
        const int row = qm + (wave << 4) + r16;
#pragma unroll
        for (int ks = 0; ks < 2; ++ks) {
            size_t off = ((size_t)(b * S) + row) * D + (h << 6) + (ks << 5) + (h2 << 3);
            qh[m][ks] = *(const short8*)(Qhi + off);
            ql[m][ks] = *(const short8*)(Qlo + off);
        }
    }

    float sum[4][4], diag[4];
#pragma unroll
    for (int m = 0; m < 4; ++m) {
        diag[m] = -1e30f;
#pragma unroll
        for (int r = 0; r < 4; ++r) sum[m][r] = 0.f;
    }

    const int jmax = min(b0 + 127, len - 1);
    for (int j0 = 0; j0 <= jmax; j0 += 64) {
        __syncthreads();
        // stage K tile hi+lo with XOR swizzle: phys chunk = lc ^ (row&7)
        {
            const int c0 = t << 1;
#pragma unroll
            for (int u = 0; u < 2; ++u) {
                int c = c0 + u;
                int row = c >> 3, lc = c & 7;
                int phys = (row << 7) + ((lc ^ (row & 7)) << 4);
                size_t g = ((size_t)(b * S) + j0 + row) * D + (h << 6) + (lc << 3);
                *(uint4*)((char*)KsHi + phys) = *(const uint4*)(Khi + g);
                *(uint4*)((char*)KsLo + phys) = *(const uint4*)(Klo + g);
            }
        }
        __syncthreads();
        if (j0 > b0 + 64) continue;  // no subtile active (uniform; qb max = b0+64)

        f32x4 acc[4][4];
#pragma unroll
        for (int m = 0; m < 4; ++m)
#pragma unroll
            for (int n = 0; n < 4; ++n) acc[m][n] = (f32x4){0.f, 0.f, 0.f, 0.f};

#pragma unroll
        for (int ks = 0; ks < 2; ++ks) {
            short8 kh[4], kl[4];
#pragma unroll
            for (int n = 0; n < 4; ++n) {
                int row = (n << 4) + r16;
                int lc = (ks << 2) + h2;
                int phys = (row << 7) + ((lc ^ (row & 7)) << 4);
                kh[n] = *(const short8*)((const char*)KsHi + phys);
                kl[n] = *(const short8*)((const char*)KsLo + phys);
            }
#pragma unroll
            for (int m = 0; m < 4; ++m) {
                const int qm = (m < 2) ? a0 + (m << 6) : b0 + ((m - 2) << 6);
                if (j0 > qm) continue;
#pragma unroll
                for (int n = 0; n < 4; ++n) {
                    if (j0 + (n << 4) > qm + (wave << 4) + 15) continue;  // fully masked
                    acc[m][n] = __builtin_amdgcn_mfma_f32_16x16x32_bf16(qh[m][ks], kh[n], acc[m][n], 0, 0, 0);
                    acc[m][n] = __builtin_amdgcn_mfma_f32_16x16x32_bf16(qh[m][ks], kl[n], acc[m][n], 0, 0, 0);
                    acc[m][n] = __builtin_amdgcn_mfma_f32_16x16x32_bf16(ql[m][ks], kh[n], acc[m][n], 0, 0, 0);
                }
            }
        }

        const bool pad = (j0 + 64 > len);
#pragma unroll
        for (int m = 0; m < 4; ++m) {
            const int qm = (m < 2) ? a0 + (m << 6) : b0 + ((m - 2) << 6);
            if (j0 > qm) continue;
            const bool causal = (j0 == qm);
            if (causal || pad) {
#pragma unroll
                for (int n = 0; n < 4; ++n)
#pragma unroll
                    for (int r = 0; r < 4; ++r) {
                        int j = j0 + (n << 4) + r16;
                        int s = qm + (wave << 4) + (h2 << 2) + r;
                        if (j > s || j >= len) acc[m][n][r] = -1e30f;
                    }
                if (causal) {
#pragma unroll
                    for (int r = 0; r < 4; ++r)
                        if (r16 == (h2 << 2) + r) {
#pragma unroll
                            for (int n = 0; n < 4; ++n)
                                if (n == wave) diag[m] = acc[m][n][r];
                        }
                }
            }
            // accumulate exp (no max subtraction: |scores| << 88)
#pragma unroll
            for (int r = 0; r < 4; ++r)
                sum[m][r] += __expf(acc[m][0][r]) + __expf(acc[m][1][r]) +
                             __expf(acc[m][2][r]) + __expf(acc[m][3][r]);
        }
    }

    // cross-lane reduce of sums (over the 16 lanes of each row group)
#pragma unroll
    for (int m = 0; m < 4; ++m)
#pragma unroll
        for (int r = 0; r < 4; ++r) {
            float sv = sum[m][r];
            sv += __shfl_xor(sv, 1);
            sv += __shfl_xor(sv, 2);
            sv += __shfl_xor(sv, 4);
            sv += __shfl_xor(sv, 8);
            sum[m][r] = sv;
        }

    // d = exp(diag)/sum  (diag lanes own rows: r16 == h2*4 + r)
#pragma unroll
    for (int m = 0; m < 4; ++m)
#pragma unroll
        for (int r = 0; r < 4; ++r)
            if (r16 == (h2 << 2) + r)
                dbuf[(m << 6) + (wave << 4) + r16] = __expf(diag[m]) / sum[m][r];
    __syncthreads();

    // weighted = d * V  (block's 256 rows: [a0,a0+128) ++ [b0,b0+128))
#pragma unroll
    for (int i = 0; i < 16; ++i) {
        int ri = i * 16 + (t >> 4);
        int col = (t & 15) * 4;
        int srow = (ri < 128) ? a0 + ri : b0 + ri - 128;
        float dv = dbuf[ri];
        const float4 v = *(const float4*)(V + ((size_t)(b * S) + srow) * D + (h << 6) + col);
        uint2 o;
        o.x = (unsigned)f2bf(v.x * dv) | ((unsigned)f2bf(v.y * dv) << 16);
        o.y = (unsigned)f2bf(v.z * dv) | ((unsigned)f2bf(v.w * dv) << 16);
        *(uint2*)(Wt + ((size_t)(b * S) + srow) * D + (h << 6) + col) = o;
    }
}

extern "C" void kernel_launch(void* const* d_in, const int* in_sizes, int n_in,
                              void* d_out, int out_size, void* d_ws, size_t ws_size,
                              hipStream_t stream) {
    const float* batch = (const float*)d_in[0];
    const int* lengths = (const int*)d_in[1];
    const float* wq = (const float*)d_in[2];
    const float* bq = (const float*)d_in[3];
    const float* wk = (const float*)d_in[4];
    const float* bk = (const float*)d_in[5];
    const float* wv = (const float*)d_in[6];
    const float* bv = (const float*)d_in[7];
    const float* w0 = (const float*)d_in[8];
    const float* b0 = (const float*)d_in[9];

    const int D = in_sizes[3];            // 1024
    const int B = in_sizes[1];            // 8
    const int S = in_sizes[0] / (B * D);  // 1024
    const int H = 16;
    const int M = B * S;                  // 8192

    char* ws = (char*)d_ws;
    u16* Ab = (u16*)ws;   ws += (size_t)M * D * 2;
    u16* wqT = (u16*)ws;  ws += (size_t)D * D * 2;
    u16* wkT = (u16*)ws;  ws += (size_t)D * D * 2;
    u16* wvT = (u16*)ws;  ws += (size_t)D * D * 2;
    u16* w0T = (u16*)ws;  ws += (size_t)D * D * 2;
    u16* Qhi = (u16*)ws;  ws += (size_t)M * D * 2;
    u16* Qlo = (u16*)ws;  ws += (size_t)M * D * 2;
    u16* Khi = (u16*)ws;  ws += (size_t)M * D * 2;
    u16* Klo = (u16*)ws;  ws += (size_t)M * D * 2;
    float* Vf = (float*)ws; ws += (size_t)M * D * 4;
    u16* Wtb = (u16*)ws;  ws += (size_t)M * D * 2;

    // 1. converts
    k_convert<<<(M * D / 8 + 255) / 256, 256, 0, stream>>>(batch, Ab, M * D / 8);
    dim3 tg(D / 64, D / 64);
    k_transpose<<<tg, 256, 0, stream>>>(wq, wqT, D);
    k_transpose<<<tg, 256, 0, stream>>>(wk, wkT, D);
    k_transpose<<<tg, 256, 0, stream>>>(wv, wvT, D);
    k_transpose<<<tg, 256, 0, stream>>>(w0, w0T, D);

    // 2. projections: Q,K -> hi/lo bf16 split; V -> f32
    dim3 gg(D / 128, M / 128);
    k_gemm<1><<<gg, 256, 0, stream>>>(Ab, wqT, bq, nullptr, Qhi, Qlo, M, D, D);
    k_gemm<1><<<gg, 256, 0, stream>>>(Ab, wkT, bk, nullptr, Khi, Klo, M, D, D);
    k_gemm<0><<<gg, 256, 0, stream>>>(Ab, wvT, bv, Vf, nullptr, nullptr, M, D, D);

    // 3. MFMA diagonal softmax + weighted = d*V
    const int nchunk = S / 128;                 // 8
    const int nblk = (nchunk / 2) * H * B;      // 512
    k_scores<<<nblk, 256, 0, stream>>>(Qhi, Qlo, Khi, Klo, Vf, lengths, Wtb, S, D, nchunk);

    // 4. output projection -> d_out (f32)
    k_gemm<0><<<gg, 256, 0, stream>>>(Wtb, w0T, b0, (float*)d_out, nullptr, nullptr, M, D, D);
}

// Round 3
// 192.616 us; speedup vs baseline: 2.4055x; 1.0469x over previous
//
#include <hip/hip_runtime.h>
#include <hip/hip_bf16.h>
#include <stdint.h>
#include <math.h>

typedef short short8 __attribute__((ext_vector_type(8)));
typedef float f32x4 __attribute__((ext_vector_type(4)));
typedef unsigned short u16;

__device__ __forceinline__ u16 f2bf(float f) {
    unsigned u = __float_as_uint(f);
    unsigned r = 0x7FFFu + ((u >> 16) & 1u);
    return (u16)((u + r) >> 16);
}
__device__ __forceinline__ float bf2f(u16 h) {
    return __uint_as_float((unsigned)h << 16);
}

#define GL_LDS16(g, l)                                                         \
    __builtin_amdgcn_global_load_lds(                                          \
        (const __attribute__((address_space(1))) void*)(g),                    \
        (__attribute__((address_space(3))) void*)(l), 16, 0, 0)

// ---------------- elementwise f32 -> bf16 convert (8 elems/thread) ----------
__global__ __launch_bounds__(256) void k_convert(const float* __restrict__ src,
                                                 u16* __restrict__ dst, int n8) {
    int i = blockIdx.x * 256 + threadIdx.x;
    if (i >= n8) return;
    const float4* s = (const float4*)src + (size_t)i * 2;
    float4 a = s[0], b = s[1];
    uint4 o;
    o.x = (unsigned)f2bf(a.x) | ((unsigned)f2bf(a.y) << 16);
    o.y = (unsigned)f2bf(a.z) | ((unsigned)f2bf(a.w) << 16);
    o.z = (unsigned)f2bf(b.x) | ((unsigned)f2bf(b.y) << 16);
    o.w = (unsigned)f2bf(b.z) | ((unsigned)f2bf(b.w) << 16);
    ((uint4*)dst)[i] = o;
}

// ---------------- transpose + convert: W[K][N] f32 -> WT[N][K] bf16 ---------
__global__ __launch_bounds__(256) void k_transpose(const float* __restrict__ W,
                                                   u16* __restrict__ WT, int Dim) {
    __shared__ float tile[64][65];
    int k0 = blockIdx.x * 64, n0 = blockIdx.y * 64;
    int t = threadIdx.x;
    int col = t & 63, rb = t >> 6;
#pragma unroll
    for (int i = 0; i < 16; ++i) {
        int r = i * 4 + rb;
        tile[r][col] = W[(size_t)(k0 + r) * Dim + n0 + col];
    }
    __syncthreads();
#pragma unroll
    for (int i = 0; i < 16; ++i) {
        int r = i * 4 + rb;
        WT[(size_t)(n0 + r) * Dim + k0 + col] = f2bf(tile[col][r]);
    }
}

// ---------------- bf16 MFMA GEMM, XCD-chunked 1D grid ----------------------
// FUSED=1: N=3*ldo, epilogue splits into {Qhi/Qlo, Khi/Klo, Vb} per 1024-col seg
// FUSED=0: f32 out C with bias b1.
// Swizzle: xcd = wg&7 owns 8 m-row-blocks x all n-cols (m-fastest in chunk)
// so the A panel (2 MB) + streamed B panels stay in the XCD's private L2.
template <int FUSED>
__global__ __launch_bounds__(256) void k_gemm(
    const u16* __restrict__ A, const u16* __restrict__ BT,
    const float* __restrict__ b1, const float* __restrict__ b2,
    const float* __restrict__ b3,
    u16* __restrict__ Qh, u16* __restrict__ Ql,
    u16* __restrict__ Kh, u16* __restrict__ Kl,
    u16* __restrict__ Vb, float* __restrict__ C,
    int K, int ldo) {
    __shared__ __align__(16) u16 As[128 * 32];
    __shared__ __align__(16) u16 Bs[128 * 32];
    const int wg = blockIdx.x;
    const int xcd = wg & 7, idc = wg >> 3;
    const int nb = idc >> 3, ml = idc & 7;     // 8 m-blocks per XCD chunk
    const int m0 = ((xcd << 3) + ml) << 7;
    const int n0 = nb << 7;
    const int t = threadIdx.x;
    const int lane = t & 63;
    const int wave = t >> 6;
    const int wr = wave >> 1, wc = wave & 1;
    const int r16 = lane & 15, kq = lane >> 4;

    f32x4 acc[4][4];
#pragma unroll
    for (int m = 0; m < 4; ++m)
#pragma unroll
        for (int n = 0; n < 4; ++n) acc[m][n] = (f32x4){0.f, 0.f, 0.f, 0.f};

    for (int kt = 0; kt < K; kt += 32) {
#pragma unroll
        for (int i = 0; i < 2; ++i) {
            int q = i * 256 + t;
            int row = q >> 2, c = (q & 3) << 3;
            GL_LDS16(A + (size_t)(m0 + row) * K + kt + c, &As[(q & ~63) * 8]);
            GL_LDS16(BT + (size_t)(n0 + row) * K + kt + c, &Bs[(q & ~63) * 8]);
        }
        __syncthreads();

        short8 a[4], bfr[4];
#pragma unroll
        for (int m = 0; m < 4; ++m)
            a[m] = *(const short8*)&As[(wr * 64 + m * 16 + r16) * 32 + kq * 8];
#pragma unroll
        for (int n = 0; n < 4; ++n)
            bfr[n] = *(const short8*)&Bs[(wc * 64 + n * 16 + r16) * 32 + kq * 8];
#pragma unroll
        for (int m = 0; m < 4; ++m)
#pragma unroll
            for (int n = 0; n < 4; ++n)
                acc[m][n] = __builtin_amdgcn_mfma_f32_16x16x32_bf16(a[m], bfr[n],
                                                                    acc[m][n], 0, 0, 0);
        __syncthreads();
    }

    if (FUSED) {
        const int seg = n0 >> 10;
        const float* bias = (seg == 0) ? b1 : (seg == 1) ? b2 : b3;
        u16* oh = (seg == 0) ? Qh : (seg == 1) ? Kh : Vb;
        u16* ol = (seg == 0) ? Ql : Kl;  // unused when seg==2
        const int nc0 = n0 & 1023;
#pragma unroll
        for (int n = 0; n < 4; ++n) {
            int col = nc0 + wc * 64 + n * 16 + r16;
            float bvv = bias[col];
#pragma unroll
            for (int m = 0; m < 4; ++m) {
                int row = m0 + wr * 64 + m * 16 + kq * 4;
#pragma unroll
                for (int j = 0; j < 4; ++j) {
                    float val = acc[m][n][j] + bvv;
                    size_t idx = (size_t)(row + j) * ldo + col;
                    u16 hi = f2bf(val);
                    oh[idx] = hi;
                    if (seg < 2) ol[idx] = f2bf(val - bf2f(hi));
                }
            }
        }
    } else {
#pragma unroll
        for (int n = 0; n < 4; ++n) {
            int col = n0 + wc * 64 + n * 16 + r16;
            float bvv = b1[col];
#pragma unroll
            for (int m = 0; m < 4; ++m) {
                int row = m0 + wr * 64 + m * 16 + kq * 4;
#pragma unroll
                for (int j = 0; j < 4; ++j)
                    C[(size_t)(row + j) * ldo + col] = acc[m][n][j] + bvv;
            }
        }
    }
}

// ---------------- MFMA diagonal-softmax + weighted = d*V --------------------
// 1024 blocks (4/CU), 256 threads = 4 waves. Block bx pairs 64-row chunk bx
// with chunk (15-bx) -> 17 active tile-units each. Same-(b,h) blocks share an
// XCD for K/Q L2 reuse. K tiles staged hi+lo via global_load_lds with
// pre-swizzled SOURCE (XOR chunk swizzle kills ds_read_b128 bank conflicts).
__global__ __launch_bounds__(256, 2) void k_scores(
    const u16* __restrict__ Qhi, const u16* __restrict__ Qlo,
    const u16* __restrict__ Khi, const u16* __restrict__ Klo,
    const u16* __restrict__ Vb, const int* __restrict__ lengths,
    u16* __restrict__ Wt, int S, int D) {
    __shared__ __align__(16) u16 KsHi[64 * 64];
    __shared__ __align__(16) u16 KsLo[64 * 64];
    __shared__ float dbuf[128];

    const int wg = blockIdx.x;
    const int xcd = wg & 7, idc = wg >> 3;
    const int bh = (xcd << 4) + (idc >> 3);    // 16 (b,h) per XCD
    const int bx = idc & 7;
    const int b = bh >> 4, h = bh & 15;
    const int nchunk = S >> 6;                 // 16
    const int a0 = bx << 6;
    const int b0 = (nchunk - 1 - bx) << 6;

    const int t = threadIdx.x;
    const int lane = t & 63, wave = t >> 6;
    const int r16 = lane & 15, h2 = lane >> 4;
    const int len = lengths[b];

    // Q fragments hi+lo: m-group 0 -> rows a0+.., 1 -> rows b0+..
    short8 qh[2][2], ql[2][2];
#pragma unroll
    for (int m = 0; m < 2; ++m) {
        const int qm = m ? b0 : a0;
        const int row = qm + (wave << 4) + r16;
#pragma unroll
        for (int ks = 0; ks < 2; ++ks) {
            size_t off = ((size_t)(b * S) + row) * D + (h << 6) + (ks << 5) + (h2 << 3);
            qh[m][ks] = *(const short8*)(Qhi + off);
            ql[m][ks] = *(const short8*)(Qlo + off);
        }
    }

    float sum[2][4];
    float diag[2] = {-1e30f, -1e30f};
#pragma unroll
    for (int m = 0; m < 2; ++m)
#pragma unroll
        for (int r = 0; r < 4; ++r) sum[m][r] = 0.f;

    const int jmax = min(b0 + 63, len - 1);
    for (int j0 = 0; j0 <= jmax; j0 += 64) {
        __syncthreads();
        // stage K tile hi+lo: dest linear, source chunk XORed (involution)
#pragma unroll
        for (int p = 0; p < 2; ++p) {
            const int base_row = p * 32 + wave * 8;       // wave-uniform
            const int row = base_row + (lane >> 3);
            const int lc = (lane & 7) ^ (row & 7);
            size_t g = ((size_t)(b * S) + j0 + row) * D + (h << 6) + (lc << 3);
            GL_LDS16(Khi + g, &KsHi[base_row * 64]);
            GL_LDS16(Klo + g, &KsLo[base_row * 64]);
        }
        __syncthreads();

        f32x4 acc[2][4];
#pragma unroll
        for (int m = 0; m < 2; ++m)
#pragma unroll
            for (int n = 0; n < 4; ++n) acc[m][n] = (f32x4){0.f, 0.f, 0.f, 0.f};

#pragma unroll
        for (int ks = 0; ks < 2; ++ks) {
            short8 kh[4], kl[4];
#pragma unroll
            for (int n = 0; n < 4; ++n) {
                int row = (n << 4) + r16;
                int lc = (ks << 2) + h2;
                int phys = (row << 7) + ((lc ^ (row & 7)) << 4);
                kh[n] = *(const short8*)((const char*)KsHi + phys);
                kl[n] = *(const short8*)((const char*)KsLo + phys);
            }
#pragma unroll
            for (int m = 0; m < 2; ++m) {
                const int qm = m ? b0 : a0;
                if (j0 > qm) continue;
#pragma unroll
                for (int n = 0; n < 4; ++n) {
                    if (j0 + (n << 4) > qm + (wave << 4) + 15) continue;  // fully masked
                    acc[m][n] = __builtin_amdgcn_mfma_f32_16x16x32_bf16(qh[m][ks], kh[n], acc[m][n], 0, 0, 0);
                    acc[m][n] = __builtin_amdgcn_mfma_f32_16x16x32_bf16(qh[m][ks], kl[n], acc[m][n], 0, 0, 0);
                    acc[m][n] = __builtin_amdgcn_mfma_f32_16x16x32_bf16(ql[m][ks], kh[n], acc[m][n], 0, 0, 0);
                }
            }
        }

        const bool pad = (j0 + 64 > len);
#pragma unroll
        for (int m = 0; m < 2; ++m) {
            const int qm = m ? b0 : a0;
            if (j0 > qm) continue;
            const bool causal = (j0 == qm);
            if (causal || pad) {
#pragma unroll
                for (int n = 0; n < 4; ++n)
#pragma unroll
                    for (int r = 0; r < 4; ++r) {
                        int j = j0 + (n << 4) + r16;
                        int s = qm + (wave << 4) + (h2 << 2) + r;
                        if (j > s || j >= len) acc[m][n][r] = -1e30f;
                    }
                if (causal) {
#pragma unroll
                    for (int r = 0; r < 4; ++r)
                        if (r16 == (h2 << 2) + r) {
#pragma unroll
                            for (int n = 0; n < 4; ++n)
                                if (n == wave) diag[m] = acc[m][n][r];
                        }
                }
            }
#pragma unroll
            for (int r = 0; r < 4; ++r)
                sum[m][r] += __expf(acc[m][0][r]) + __expf(acc[m][1][r]) +
                             __expf(acc[m][2][r]) + __expf(acc[m][3][r]);
        }
    }

    // reduce sums over the 16 j-lanes (r16); h2 groups hold distinct rows
#pragma unroll
    for (int m = 0; m < 2; ++m)
#pragma unroll
        for (int r = 0; r < 4; ++r) {
            float sv = sum[m][r];
            sv += __shfl_xor(sv, 1);
            sv += __shfl_xor(sv, 2);
            sv += __shfl_xor(sv, 4);
            sv += __shfl_xor(sv, 8);
            sum[m][r] = sv;
        }

#pragma unroll
    for (int m = 0; m < 2; ++m)
#pragma unroll
        for (int r = 0; r < 4; ++r)
            if (r16 == (h2 << 2) + r)
                dbuf[(m << 6) + (wave << 4) + r16] = __expf(diag[m]) / sum[m][r];
    __syncthreads();

    // weighted = d * V for the block's 128 rows (bf16 in, bf16 out)
#pragma unroll
    for (int i = 0; i < 8; ++i) {
        int ri = i * 16 + (t >> 4);
        int c4 = (t & 15) << 2;
        int srow = (ri < 64) ? a0 + ri : b0 + ri - 64;
        float dv = dbuf[ri];
        const uint2 vv = *(const uint2*)(Vb + ((size_t)(b * S) + srow) * D + (h << 6) + c4);
        float x0 = bf2f((u16)(vv.x & 0xffffu)), x1 = bf2f((u16)(vv.x >> 16));
        float x2 = bf2f((u16)(vv.y & 0xffffu)), x3 = bf2f((u16)(vv.y >> 16));
        uint2 o;
        o.x = (unsigned)f2bf(x0 * dv) | ((unsigned)f2bf(x1 * dv) << 16);
        o.y = (unsigned)f2bf(x2 * dv) | ((unsigned)f2bf(x3 * dv) << 16);
        *(uint2*)(Wt + ((size_t)(b * S) + srow) * D + (h << 6) + c4) = o;
    }
}

extern "C" void kernel_launch(void* const* d_in, const int* in_sizes, int n_in,
                              void* d_out, int out_size, void* d_ws, size_t ws_size,
                              hipStream_t stream) {
    const float* batch = (const float*)d_in[0];
    const int* lengths = (const int*)d_in[1];
    const float* wq = (const float*)d_in[2];
    const float* bq = (const float*)d_in[3];
    const float* wk = (const float*)d_in[4];
    const float* bk = (const float*)d_in[5];
    const float* wv = (const float*)d_in[6];
    const float* bv = (const float*)d_in[7];
    const float* w0 = (const float*)d_in[8];
    const float* b0 = (const float*)d_in[9];

    const int D = in_sizes[3];            // 1024
    const int B = in_sizes[1];            // 8
    const int S = in_sizes[0] / (B * D);  // 1024
    const int H = 16;
    const int M = B * S;                  // 8192

    char* ws = (char*)d_ws;
    u16* Ab = (u16*)ws;    ws += (size_t)M * D * 2;
    u16* wcat = (u16*)ws;  ws += (size_t)3 * D * D * 2;   // [wqT; wkT; wvT]
    u16* w0T = (u16*)ws;   ws += (size_t)D * D * 2;
    u16* Qhi = (u16*)ws;   ws += (size_t)M * D * 2;
    u16* Qlo = (u16*)ws;   ws += (size_t)M * D * 2;
    u16* Khi = (u16*)ws;   ws += (size_t)M * D * 2;
    u16* Klo = (u16*)ws;   ws += (size_t)M * D * 2;
    u16* Vb = (u16*)ws;    ws += (size_t)M * D * 2;
    u16* Wtb = (u16*)ws;   ws += (size_t)M * D * 2;

    // 1. converts
    k_convert<<<(M * D / 8 + 255) / 256, 256, 0, stream>>>(batch, Ab, M * D / 8);
    dim3 tg(D / 64, D / 64);
    k_transpose<<<tg, 256, 0, stream>>>(wq, wcat, D);
    k_transpose<<<tg, 256, 0, stream>>>(wk, wcat + (size_t)D * D, D);
    k_transpose<<<tg, 256, 0, stream>>>(wv, wcat + (size_t)2 * D * D, D);
    k_transpose<<<tg, 256, 0, stream>>>(w0, w0T, D);

    // 2. fused QKV projection: N=3072, 1536 blocks, XCD-chunked
    k_gemm<1><<<(M / 128) * (3 * D / 128), 256, 0, stream>>>(
        Ab, wcat, bq, bk, bv, Qhi, Qlo, Khi, Klo, Vb, nullptr, D, D);

    // 3. MFMA diagonal softmax + weighted = d*V
    k_scores<<<(S / 128) * H * B, 256, 0, stream>>>(Qhi, Qlo, Khi, Klo, Vb,
                                                    lengths, Wtb, S, D);

    // 4. output projection -> d_out (f32), 512 blocks, XCD-chunked
    k_gemm<0><<<(M / 128) * (D / 128), 256, 0, stream>>>(
        Wtb, w0T, b0, nullptr, nullptr, nullptr, nullptr, nullptr, nullptr, nullptr,
        (float*)d_out, D, D);
}

// Round 4
// 186.768 us; speedup vs baseline: 2.4808x; 1.0313x over previous
//
#include <hip/hip_runtime.h>
#include <hip/hip_bf16.h>
#include <stdint.h>
#include <math.h>

typedef short short8 __attribute__((ext_vector_type(8)));
typedef float f32x4 __attribute__((ext_vector_type(4)));
typedef unsigned short u16;

__device__ __forceinline__ u16 f2bf(float f) {
    unsigned u = __float_as_uint(f);
    unsigned r = 0x7FFFu + ((u >> 16) & 1u);
    return (u16)((u + r) >> 16);
}
__device__ __forceinline__ float bf2f(u16 h) {
    return __uint_as_float((unsigned)h << 16);
}

#define GL_LDS16(g, l)                                                         \
    __builtin_amdgcn_global_load_lds(                                          \
        (const __attribute__((address_space(1))) void*)(g),                    \
        (__attribute__((address_space(3))) void*)(l), 16, 0, 0)

// ---------------- elementwise f32 -> bf16 convert (8 elems/thread) ----------
__global__ __launch_bounds__(256) void k_convert(const float* __restrict__ src,
                                                 u16* __restrict__ dst, int n8) {
    int i = blockIdx.x * 256 + threadIdx.x;
    if (i >= n8) return;
    const float4* s = (const float4*)src + (size_t)i * 2;
    float4 a = s[0], b = s[1];
    uint4 o;
    o.x = (unsigned)f2bf(a.x) | ((unsigned)f2bf(a.y) << 16);
    o.y = (unsigned)f2bf(a.z) | ((unsigned)f2bf(a.w) << 16);
    o.z = (unsigned)f2bf(b.x) | ((unsigned)f2bf(b.y) << 16);
    o.w = (unsigned)f2bf(b.z) | ((unsigned)f2bf(b.w) << 16);
    ((uint4*)dst)[i] = o;
}

// ---------------- transpose + convert: W[K][N] f32 -> WT[N][K] bf16 ---------
__global__ __launch_bounds__(256) void k_transpose(const float* __restrict__ W,
                                                   u16* __restrict__ WT, int Dim) {
    __shared__ float tile[64][65];
    int k0 = blockIdx.x * 64, n0 = blockIdx.y * 64;
    int t = threadIdx.x;
    int col = t & 63, rb = t >> 6;
#pragma unroll
    for (int i = 0; i < 16; ++i) {
        int r = i * 4 + rb;
        tile[r][col] = W[(size_t)(k0 + r) * Dim + n0 + col];
    }
    __syncthreads();
#pragma unroll
    for (int i = 0; i < 16; ++i) {
        int r = i * 4 + rb;
        WT[(size_t)(n0 + r) * Dim + k0 + col] = f2bf(tile[col][r]);
    }
}

// ---------------- bf16 MFMA GEMM, XCD-chunked 1D grid, 2-phase dbuf --------
// FUSED=1: N=3*ldo, epilogue splits into {Qhi/Qlo, Khi/Klo, Vb} per 1024-col seg
// FUSED=0: f32 out C with bias b1.
// Swizzle: xcd = wg&7 owns 8 m-row-blocks x all n-cols (m-fastest in chunk)
// so the A panel (2 MB) + streamed B panels stay in the XCD's private L2.
// K-loop: double-buffered LDS; STAGE(next) issued before compute(cur); one
// __syncthreads (vmcnt(0)+lgkmcnt(0)+barrier) per K-step hides load latency.
template <int FUSED>
__global__ __launch_bounds__(256) void k_gemm(
    const u16* __restrict__ A, const u16* __restrict__ BT,
    const float* __restrict__ b1, const float* __restrict__ b2,
    const float* __restrict__ b3,
    u16* __restrict__ Qh, u16* __restrict__ Ql,
    u16* __restrict__ Kh, u16* __restrict__ Kl,
    u16* __restrict__ Vb, float* __restrict__ C,
    int K, int ldo) {
    __shared__ __align__(16) u16 As[2][128 * 32];
    __shared__ __align__(16) u16 Bs[2][128 * 32];
    const int wg = blockIdx.x;
    const int xcd = wg & 7, idc = wg >> 3;
    const int nb = idc >> 3, ml = idc & 7;     // 8 m-blocks per XCD chunk
    const int m0 = ((xcd << 3) + ml) << 7;
    const int n0 = nb << 7;
    const int t = threadIdx.x;
    const int lane = t & 63;
    const int wave = t >> 6;
    const int wr = wave >> 1, wc = wave & 1;
    const int r16 = lane & 15, kq = lane >> 4;

    // staging addresses (invariant parts)
    const int q0r = t >> 2, q0c = (t & 3) << 3;          // i=0 slot
    const int q1r = (256 + t) >> 2, q1c = q0c;           // i=1 slot
    const int d0 = (t & ~63) * 8;                        // wave-uniform dest, i=0
    const int d1 = ((256 + t) & ~63) * 8;                // wave-uniform dest, i=1

    f32x4 acc[4][4];
#pragma unroll
    for (int m = 0; m < 4; ++m)
#pragma unroll
        for (int n = 0; n < 4; ++n) acc[m][n] = (f32x4){0.f, 0.f, 0.f, 0.f};

#define STAGE(buf, kt)                                                          \
    do {                                                                        \
        GL_LDS16(A + (size_t)(m0 + q0r) * K + (kt) + q0c, &As[buf][d0]);        \
        GL_LDS16(BT + (size_t)(n0 + q0r) * K + (kt) + q0c, &Bs[buf][d0]);       \
        GL_LDS16(A + (size_t)(m0 + q1r) * K + (kt) + q1c, &As[buf][d1]);        \
        GL_LDS16(BT + (size_t)(n0 + q1r) * K + (kt) + q1c, &Bs[buf][d1]);       \
    } while (0)

    STAGE(0, 0);
    __syncthreads();
    int cur = 0;
    for (int kt = 0; kt < K; kt += 32) {
        if (kt + 32 < K) STAGE(cur ^ 1, kt + 32);   // prefetch in flight
        short8 a[4], bfr[4];
#pragma unroll
        for (int m = 0; m < 4; ++m)
            a[m] = *(const short8*)&As[cur][(wr * 64 + m * 16 + r16) * 32 + kq * 8];
#pragma unroll
        for (int n = 0; n < 4; ++n)
            bfr[n] = *(const short8*)&Bs[cur][(wc * 64 + n * 16 + r16) * 32 + kq * 8];
#pragma unroll
        for (int m = 0; m < 4; ++m)
#pragma unroll
            for (int n = 0; n < 4; ++n)
                acc[m][n] = __builtin_amdgcn_mfma_f32_16x16x32_bf16(a[m], bfr[n],
                                                                    acc[m][n], 0, 0, 0);
        __syncthreads();   // drains vmcnt(0): next tile complete; protects cur
        cur ^= 1;
    }
#undef STAGE

    if (FUSED) {
        const int seg = n0 >> 10;
        const float* bias = (seg == 0) ? b1 : (seg == 1) ? b2 : b3;
        u16* oh = (seg == 0) ? Qh : (seg == 1) ? Kh : Vb;
        u16* ol = (seg == 0) ? Ql : Kl;  // unused when seg==2
        const int nc0 = n0 & 1023;
#pragma unroll
        for (int n = 0; n < 4; ++n) {
            int col = nc0 + wc * 64 + n * 16 + r16;
            float bvv = bias[col];
#pragma unroll
            for (int m = 0; m < 4; ++m) {
                int row = m0 + wr * 64 + m * 16 + kq * 4;
#pragma unroll
                for (int j = 0; j < 4; ++j) {
                    float val = acc[m][n][j] + bvv;
                    size_t idx = (size_t)(row + j) * ldo + col;
                    u16 hi = f2bf(val);
                    oh[idx] = hi;
                    if (seg < 2) ol[idx] = f2bf(val - bf2f(hi));
                }
            }
        }
    } else {
#pragma unroll
        for (int n = 0; n < 4; ++n) {
            int col = n0 + wc * 64 + n * 16 + r16;
            float bvv = b1[col];
#pragma unroll
            for (int m = 0; m < 4; ++m) {
                int row = m0 + wr * 64 + m * 16 + kq * 4;
#pragma unroll
                for (int j = 0; j < 4; ++j)
                    C[(size_t)(row + j) * ldo + col] = acc[m][n][j] + bvv;
            }
        }
    }
}

// ---------------- MFMA diagonal-softmax + weighted = d*V --------------------
// 1024 blocks (4/CU), 256 threads = 4 waves. Block bx pairs 64-row chunk bx
// with chunk (15-bx) -> 17 active tile-units each. Same-(b,h) blocks share an
// XCD for K/Q L2 reuse. K tiles staged hi+lo via global_load_lds with
// pre-swizzled SOURCE (XOR chunk swizzle kills ds_read_b128 bank conflicts).
__global__ __launch_bounds__(256, 2) void k_scores(
    const u16* __restrict__ Qhi, const u16* __restrict__ Qlo,
    const u16* __restrict__ Khi, const u16* __restrict__ Klo,
    const u16* __restrict__ Vb, const int* __restrict__ lengths,
    u16* __restrict__ Wt, int S, int D) {
    __shared__ __align__(16) u16 KsHi[64 * 64];
    __shared__ __align__(16) u16 KsLo[64 * 64];
    __shared__ float dbuf[128];

    const int wg = blockIdx.x;
    const int xcd = wg & 7, idc = wg >> 3;
    const int bh = (xcd << 4) + (idc >> 3);    // 16 (b,h) per XCD
    const int bx = idc & 7;
    const int b = bh >> 4, h = bh & 15;
    const int nchunk = S >> 6;                 // 16
    const int a0 = bx << 6;
    const int b0 = (nchunk - 1 - bx) << 6;

    const int t = threadIdx.x;
    const int lane = t & 63, wave = t >> 6;
    const int r16 = lane & 15, h2 = lane >> 4;
    const int len = lengths[b];

    // Q fragments hi+lo: m-group 0 -> rows a0+.., 1 -> rows b0+..
    short8 qh[2][2], ql[2][2];
#pragma unroll
    for (int m = 0; m < 2; ++m) {
        const int qm = m ? b0 : a0;
        const int row = qm + (wave << 4) + r16;
#pragma unroll
        for (int ks = 0; ks < 2; ++ks) {
            size_t off = ((size_t)(b * S) + row) * D + (h << 6) + (ks << 5) + (h2 << 3);
            qh[m][ks] = *(const short8*)(Qhi + off);
            ql[m][ks] = *(const short8*)(Qlo + off);
        }
    }

    float sum[2][4];
    float diag[2] = {-1e30f, -1e30f};
#pragma unroll
    for (int m = 0; m < 2; ++m)
#pragma unroll
        for (int r = 0; r < 4; ++r) sum[m][r] = 0.f;

    const int jmax = min(b0 + 63, len - 1);
    for (int j0 = 0; j0 <= jmax; j0 += 64) {
        __syncthreads();
        // stage K tile hi+lo: dest linear, source chunk XORed (involution)
#pragma unroll
        for (int p = 0; p < 2; ++p) {
            const int base_row = p * 32 + wave * 8;       // wave-uniform
            const int row = base_row + (lane >> 3);
            const int lc = (lane & 7) ^ (row & 7);
            size_t g = ((size_t)(b * S) + j0 + row) * D + (h << 6) + (lc << 3);
            GL_LDS16(Khi + g, &KsHi[base_row * 64]);
            GL_LDS16(Klo + g, &KsLo[base_row * 64]);
        }
        __syncthreads();

        f32x4 acc[2][4];
#pragma unroll
        for (int m = 0; m < 2; ++m)
#pragma unroll
            for (int n = 0; n < 4; ++n) acc[m][n] = (f32x4){0.f, 0.f, 0.f, 0.f};

#pragma unroll
        for (int ks = 0; ks < 2; ++ks) {
            short8 kh[4], kl[4];
#pragma unroll
            for (int n = 0; n < 4; ++n) {
                int row = (n << 4) + r16;
                int lc = (ks << 2) + h2;
                int phys = (row << 7) + ((lc ^ (row & 7)) << 4);
                kh[n] = *(const short8*)((const char*)KsHi + phys);
                kl[n] = *(const short8*)((const char*)KsLo + phys);
            }
#pragma unroll
            for (int m = 0; m < 2; ++m) {
                const int qm = m ? b0 : a0;
                if (j0 > qm) continue;
#pragma unroll
                for (int n = 0; n < 4; ++n) {
                    if (j0 + (n << 4) > qm + (wave << 4) + 15) continue;  // fully masked
                    acc[m][n] = __builtin_amdgcn_mfma_f32_16x16x32_bf16(qh[m][ks], kh[n], acc[m][n], 0, 0, 0);
                    acc[m][n] = __builtin_amdgcn_mfma_f32_16x16x32_bf16(qh[m][ks], kl[n], acc[m][n], 0, 0, 0);
                    acc[m][n] = __builtin_amdgcn_mfma_f32_16x16x32_bf16(ql[m][ks], kh[n], acc[m][n], 0, 0, 0);
                }
            }
        }

        const bool pad = (j0 + 64 > len);
#pragma unroll
        for (int m = 0; m < 2; ++m) {
            const int qm = m ? b0 : a0;
            if (j0 > qm) continue;
            const bool causal = (j0 == qm);
            if (causal || pad) {
#pragma unroll
                for (int n = 0; n < 4; ++n)
#pragma unroll
                    for (int r = 0; r < 4; ++r) {
                        int j = j0 + (n << 4) + r16;
                        int s = qm + (wave << 4) + (h2 << 2) + r;
                        if (j > s || j >= len) acc[m][n][r] = -1e30f;
                    }
                if (causal) {
#pragma unroll
                    for (int r = 0; r < 4; ++r)
                        if (r16 == (h2 << 2) + r) {
#pragma unroll
                            for (int n = 0; n < 4; ++n)
                                if (n == wave) diag[m] = acc[m][n][r];
                        }
                }
            }
#pragma unroll
            for (int r = 0; r < 4; ++r)
                sum[m][r] += __expf(acc[m][0][r]) + __expf(acc[m][1][r]) +
                             __expf(acc[m][2][r]) + __expf(acc[m][3][r]);
        }
    }

    // reduce sums over the 16 j-lanes (r16); h2 groups hold distinct rows
#pragma unroll
    for (int m = 0; m < 2; ++m)
#pragma unroll
        for (int r = 0; r < 4; ++r) {
            float sv = sum[m][r];
            sv += __shfl_xor(sv, 1);
            sv += __shfl_xor(sv, 2);
            sv += __shfl_xor(sv, 4);
            sv += __shfl_xor(sv, 8);
            sum[m][r] = sv;
        }

#pragma unroll
    for (int m = 0; m < 2; ++m)
#pragma unroll
        for (int r = 0; r < 4; ++r)
            if (r16 == (h2 << 2) + r)
                dbuf[(m << 6) + (wave << 4) + r16] = __expf(diag[m]) / sum[m][r];
    __syncthreads();

    // weighted = d * V for the block's 128 rows (bf16 in, bf16 out)
#pragma unroll
    for (int i = 0; i < 8; ++i) {
        int ri = i * 16 + (t >> 4);
        int c4 = (t & 15) << 2;
        int srow = (ri < 64) ? a0 + ri : b0 + ri - 64;
        float dv = dbuf[ri];
        const uint2 vv = *(const uint2*)(Vb + ((size_t)(b * S) + srow) * D + (h << 6) + c4);
        float x0 = bf2f((u16)(vv.x & 0xffffu)), x1 = bf2f((u16)(vv.x >> 16));
        float x2 = bf2f((u16)(vv.y & 0xffffu)), x3 = bf2f((u16)(vv.y >> 16));
        uint2 o;
        o.x = (unsigned)f2bf(x0 * dv) | ((unsigned)f2bf(x1 * dv) << 16);
        o.y = (unsigned)f2bf(x2 * dv) | ((unsigned)f2bf(x3 * dv) << 16);
        *(uint2*)(Wt + ((size_t)(b * S) + srow) * D + (h << 6) + c4) = o;
    }
}

extern "C" void kernel_launch(void* const* d_in, const int* in_sizes, int n_in,
                              void* d_out, int out_size, void* d_ws, size_t ws_size,
                              hipStream_t stream) {
    const float* batch = (const float*)d_in[0];
    const int* lengths = (const int*)d_in[1];
    const float* wq = (const float*)d_in[2];
    const float* bq = (const float*)d_in[3];
    const float* wk = (const float*)d_in[4];
    const float* bk = (const float*)d_in[5];
    const float* wv = (const float*)d_in[6];
    const float* bv = (const float*)d_in[7];
    const float* w0 = (const float*)d_in[8];
    const float* b0 = (const float*)d_in[9];

    const int D = in_sizes[3];            // 1024
    const int B = in_sizes[1];            // 8
    const int S = in_sizes[0] / (B * D);  // 1024
    const int H = 16;
    const int M = B * S;                  // 8192

    char* ws = (char*)d_ws;
    u16* Ab = (u16*)ws;    ws += (size_t)M * D * 2;
    u16* wcat = (u16*)ws;  ws += (size_t)3 * D * D * 2;   // [wqT; wkT; wvT]
    u16* w0T = (u16*)ws;   ws += (size_t)D * D * 2;
    u16* Qhi = (u16*)ws;   ws += (size_t)M * D * 2;
    u16* Qlo = (u16*)ws;   ws += (size_t)M * D * 2;
    u16* Khi = (u16*)ws;   ws += (size_t)M * D * 2;
    u16* Klo = (u16*)ws;   ws += (size_t)M * D * 2;
    u16* Vb = (u16*)ws;    ws += (size_t)M * D * 2;
    u16* Wtb = (u16*)ws;   ws += (size_t)M * D * 2;

    // 1. converts
    k_convert<<<(M * D / 8 + 255) / 256, 256, 0, stream>>>(batch, Ab, M * D / 8);
    dim3 tg(D / 64, D / 64);
    k_transpose<<<tg, 256, 0, stream>>>(wq, wcat, D);
    k_transpose<<<tg, 256, 0, stream>>>(wk, wcat + (size_t)D * D, D);
    k_transpose<<<tg, 256, 0, stream>>>(wv, wcat + (size_t)2 * D * D, D);
    k_transpose<<<tg, 256, 0, stream>>>(w0, w0T, D);

    // 2. fused QKV projection: N=3072, 1536 blocks, XCD-chunked
    k_gemm<1><<<(M / 128) * (3 * D / 128), 256, 0, stream>>>(
        Ab, wcat, bq, bk, bv, Qhi, Qlo, Khi, Klo, Vb, nullptr, D, D);

    // 3. MFMA diagonal softmax + weighted = d*V
    k_scores<<<(S / 128) * H * B, 256, 0, stream>>>(Qhi, Qlo, Khi, Klo, Vb,
                                                    lengths, Wtb, S, D);

    // 4. output projection -> d_out (f32), 512 blocks, XCD-chunked
    k_gemm<0><<<(M / 128) * (D / 128), 256, 0, stream>>>(
        Wtb, w0T, b0, nullptr, nullptr, nullptr, nullptr, nullptr, nullptr, nullptr,
        (float*)d_out, D, D);
}

// Round 6
// 180.748 us; speedup vs baseline: 2.5634x; 1.0333x over previous
//
#include <hip/hip_runtime.h>
#include <hip/hip_bf16.h>
#include <stdint.h>
#include <math.h>

typedef short short8 __attribute__((ext_vector_type(8)));
typedef float f32x4 __attribute__((ext_vector_type(4)));
typedef unsigned short u16;

__device__ __forceinline__ u16 f2bf(float f) {
    unsigned u = __float_as_uint(f);
    unsigned r = 0x7FFFu + ((u >> 16) & 1u);
    return (u16)((u + r) >> 16);
}
__device__ __forceinline__ float bf2f(u16 h) {
    return __uint_as_float((unsigned)h << 16);
}

#define GL_LDS16(g, l)                                                         \
    __builtin_amdgcn_global_load_lds(                                          \
        (const __attribute__((address_space(1))) void*)(g),                    \
        (__attribute__((address_space(3))) void*)(l), 16, 0, 0)

// ---------------- elementwise f32 -> bf16 convert (8 elems/thread) ----------
__global__ __launch_bounds__(256) void k_convert(const float* __restrict__ src,
                                                 u16* __restrict__ dst, int n8) {
    int i = blockIdx.x * 256 + threadIdx.x;
    if (i >= n8) return;
    const float4* s = (const float4*)src + (size_t)i * 2;
    float4 a = s[0], b = s[1];
    uint4 o;
    o.x = (unsigned)f2bf(a.x) | ((unsigned)f2bf(a.y) << 16);
    o.y = (unsigned)f2bf(a.z) | ((unsigned)f2bf(a.w) << 16);
    o.z = (unsigned)f2bf(b.x) | ((unsigned)f2bf(b.y) << 16);
    o.w = (unsigned)f2bf(b.z) | ((unsigned)f2bf(b.w) << 16);
    ((uint4*)dst)[i] = o;
}

// ---------------- transpose + convert: W[K][N] f32 -> WT[N][K] bf16 ---------
__global__ __launch_bounds__(256) void k_transpose(const float* __restrict__ W,
                                                   u16* __restrict__ WT, int Dim) {
    __shared__ float tile[64][65];
    int k0 = blockIdx.x * 64, n0 = blockIdx.y * 64;
    int t = threadIdx.x;
    int col = t & 63, rb = t >> 6;
#pragma unroll
    for (int i = 0; i < 16; ++i) {
        int r = i * 4 + rb;
        tile[r][col] = W[(size_t)(k0 + r) * Dim + n0 + col];
    }
    __syncthreads();
#pragma unroll
    for (int i = 0; i < 16; ++i) {
        int r = i * 4 + rb;
        WT[(size_t)(n0 + r) * Dim + k0 + col] = f2bf(tile[col][r]);
    }
}

// ---------------- phase-pipelined bf16 MFMA GEMM: BM=256, BN=128, BK=64 -----
// 512 threads = 8 waves (4M x 2N); per-wave output 64x64 (4m x 4n frags).
// LDS ks-major halves: A[2buf][2ks][256x32], B[2buf][2ks][128x32] (96 KiB).
// 4 phases per K-tile, quadrant (ks, mh): 8 MFMA, A2 (+B4 at mh0) ds_read_b128.
// One half-tile staged per phase at lead-5; s_waitcnt vmcnt(5) at even phases
// (3 half-tiles in flight, never drained to 0 in the main loop).
// 16B-slot XOR swizzle (slot ^= (row>>1)&3) applied on global SOURCE at stage
// and on LDS address at read -> stride-64B ds_read_b128 is 2-way = free.
// FUSED=1: N=3*ldo, epilogue splits {Qhi/Qlo, Khi/Kl, Vb} per 1024-col seg.
// FUSED=0: f32 out C with bias b1.
template <int FUSED>
__global__ __launch_bounds__(512) void k_gemm8(
    const u16* __restrict__ A, const u16* __restrict__ BT,
    const float* __restrict__ b1, const float* __restrict__ b2,
    const float* __restrict__ b3,
    u16* __restrict__ Qh, u16* __restrict__ Ql,
    u16* __restrict__ Kh, u16* __restrict__ Kl,
    u16* __restrict__ Vb, float* __restrict__ C,
    int K, int ldo) {
    __shared__ __align__(16) u16 Asub[2][2][256 * 32];
    __shared__ __align__(16) u16 Bsub[2][2][128 * 32];

    const int wg = blockIdx.x;
    const int xcd = wg & 7, idc = wg >> 3;          // grid % 8 == 0
    const int ml = idc & 3, nbn = idc >> 2;         // 4 m-tiles per XCD chunk
    const int m0 = ((xcd << 2) + ml) << 8;          // *256
    const int n0 = nbn << 7;                        // *128
    const int t = threadIdx.x;
    const int lane = t & 63, wave = t >> 6;
    const int wr = wave >> 1, wc = wave & 1;
    const int r16 = lane & 15, kq = lane >> 4;
    const int nt = K >> 6;                          // K-tiles (16)

    // fragment LDS offsets (u16 units within one [rows][32] region), swizzled
    int offA[4], offB[4];
#pragma unroll
    for (int mi = 0; mi < 4; ++mi) {
        int row = wr * 64 + mi * 16 + r16;
        offA[mi] = row * 32 + ((kq ^ ((row >> 1) & 3)) << 3);
    }
#pragma unroll
    for (int n = 0; n < 4; ++n) {
        int row = wc * 64 + n * 16 + r16;
        offB[n] = row * 32 + ((kq ^ ((row >> 1) & 3)) << 3);
    }

    f32x4 acc[4][4];
#pragma unroll
    for (int m = 0; m < 4; ++m)
#pragma unroll
        for (int n = 0; n < 4; ++n) acc[m][n] = (f32x4){0.f, 0.f, 0.f, 0.f};

    // stage half-tile q: tile q>>2, type q&3 (0:A-ks0 1:B-ks0 2:A-ks1 3:B-ks1)
    auto stage = [&](int q) {
        const int tile = q >> 2, typ = q & 3;
        const int buf = tile & 1, ks = typ >> 1;
        const int kt = ((tile < nt ? tile : nt - 1) << 6) + (ks << 5);
        if (!(typ & 1)) {  // A half: 16 KB = 2 loads/thread
#pragma unroll
            for (int r = 0; r < 2; ++r) {
                int li = (r << 9) + t;
                int row = li >> 2;
                int kk = ((li & 3) ^ ((row >> 1) & 3)) << 3;
                GL_LDS16(A + (size_t)(m0 + row) * K + kt + kk,
                         &Asub[buf][ks][(li & ~63) << 3]);
            }
        } else {           // B half: 8 KB = 1 load/thread
            int li = t;
            int row = li >> 2;
            int kk = ((li & 3) ^ ((row >> 1) & 3)) << 3;
            GL_LDS16(BT + (size_t)(n0 + row) * K + kt + kk,
                     &Bsub[buf][ks][(li & ~63) << 3]);
        }
    };

    // prologue: HT0..4 (tile0 complete + tile1 A-ks0) -> 8 loads/thread
    for (int q = 0; q < 5; ++q) stage(q);

    short8 bfr[4];
    for (int tile = 0; tile < nt; ++tile) {
        const int buf = tile & 1;
#pragma unroll
        for (int ph = 0; ph < 4; ++ph) {
            const int ks = ph >> 1, mh = ph & 1;
            if (!(ph & 1)) asm volatile("s_waitcnt vmcnt(5)" ::: "memory");
            __builtin_amdgcn_sched_barrier(0);
            __builtin_amdgcn_s_barrier();
            __builtin_amdgcn_sched_barrier(0);
            const u16* Ar = Asub[buf][ks];
            short8 a0 = *(const short8*)(Ar + offA[2 * mh]);
            short8 a1 = *(const short8*)(Ar + offA[2 * mh + 1]);
            if (mh == 0) {
                const u16* Br = Bsub[buf][ks];
#pragma unroll
                for (int n = 0; n < 4; ++n)
                    bfr[n] = *(const short8*)(Br + offB[n]);
            }
            stage(tile * 4 + ph + 5);
            __builtin_amdgcn_s_setprio(1);
#pragma unroll
            for (int n = 0; n < 4; ++n) {
                acc[2 * mh][n] = __builtin_amdgcn_mfma_f32_16x16x32_bf16(
                    a0, bfr[n], acc[2 * mh][n], 0, 0, 0);
                acc[2 * mh + 1][n] = __builtin_amdgcn_mfma_f32_16x16x32_bf16(
                    a1, bfr[n], acc[2 * mh + 1][n], 0, 0, 0);
            }
            __builtin_amdgcn_s_setprio(0);
        }
    }
    asm volatile("s_waitcnt vmcnt(0)" ::: "memory");

    if (FUSED) {
        const int seg = n0 >> 10;
        const float* bias = (seg == 0) ? b1 : (seg == 1) ? b2 : b3;
        u16* oh = (seg == 0) ? Qh : (seg == 1) ? Kh : Vb;
        u16* ol = (seg == 0) ? Ql : Kl;  // unused when seg==2
        const int nc0 = n0 & 1023;
#pragma unroll
        for (int n = 0; n < 4; ++n) {
            int col = nc0 + wc * 64 + n * 16 + r16;
            float bvv = bias[col];
#pragma unroll
            for (int mi = 0; mi < 4; ++mi) {
                int row = m0 + wr * 64 + mi * 16 + kq * 4;
#pragma unroll
                for (int j = 0; j < 4; ++j) {
                    float val = acc[mi][n][j] + bvv;
                    size_t idx = (size_t)(row + j) * ldo + col;
                    u16 hi = f2bf(val);
                    oh[idx] = hi;
                    if (seg < 2) ol[idx] = f2bf(val - bf2f(hi));
                }
            }
        }
    } else {
#pragma unroll
        for (int n = 0; n < 4; ++n) {
            int col = n0 + wc * 64 + n * 16 + r16;
            float bvv = b1[col];
#pragma unroll
            for (int mi = 0; mi < 4; ++mi) {
                int row = m0 + wr * 64 + mi * 16 + kq * 4;
#pragma unroll
                for (int j = 0; j < 4; ++j)
                    C[(size_t)(row + j) * ldo + col] = acc[mi][n][j] + bvv;
            }
        }
    }
}

// ---------------- MFMA diagonal-softmax + weighted = d*V --------------------
// 1024 blocks (4/CU), 256 threads = 4 waves. Block bx pairs 64-row chunk bx
// with chunk (15-bx) -> uniform work. Same-(b,h) blocks share an XCD.
__global__ __launch_bounds__(256, 2) void k_scores(
    const u16* __restrict__ Qhi, const u16* __restrict__ Qlo,
    const u16* __restrict__ Khi, const u16* __restrict__ Klo,
    const u16* __restrict__ Vb, const int* __restrict__ lengths,
    u16* __restrict__ Wt, int S, int D) {
    __shared__ __align__(16) u16 KsHi[64 * 64];
    __shared__ __align__(16) u16 KsLo[64 * 64];
    __shared__ float dbuf[128];

    const int wg = blockIdx.x;
    const int xcd = wg & 7, idc = wg >> 3;
    const int bh = (xcd << 4) + (idc >> 3);    // 16 (b,h) per XCD
    const int bx = idc & 7;
    const int b = bh >> 4, h = bh & 15;
    const int nchunk = S >> 6;                 // 16
    const int a0 = bx << 6;
    const int b0 = (nchunk - 1 - bx) << 6;

    const int t = threadIdx.x;
    const int lane = t & 63, wave = t >> 6;
    const int r16 = lane & 15, h2 = lane >> 4;
    const int len = lengths[b];

    short8 qh[2][2], ql[2][2];
#pragma unroll
    for (int m = 0; m < 2; ++m) {
        const int qm = m ? b0 : a0;
        const int row = qm + (wave << 4) + r16;
#pragma unroll
        for (int ks = 0; ks < 2; ++ks) {
            size_t off = ((size_t)(b * S) + row) * D + (h << 6) + (ks << 5) + (h2 << 3);
            qh[m][ks] = *(const short8*)(Qhi + off);
            ql[m][ks] = *(const short8*)(Qlo + off);
        }
    }

    float sum[2][4];
    float diag[2] = {-1e30f, -1e30f};
#pragma unroll
    for (int m = 0; m < 2; ++m)
#pragma unroll
        for (int r = 0; r < 4; ++r) sum[m][r] = 0.f;

    const int jmax = min(b0 + 63, len - 1);
    for (int j0 = 0; j0 <= jmax; j0 += 64) {
        __syncthreads();
#pragma unroll
        for (int p = 0; p < 2; ++p) {
            const int base_row = p * 32 + wave * 8;       // wave-uniform
            const int row = base_row + (lane >> 3);
            const int lc = (lane & 7) ^ (row & 7);
            size_t g = ((size_t)(b * S) + j0 + row) * D + (h << 6) + (lc << 3);
            GL_LDS16(Khi + g, &KsHi[base_row * 64]);
            GL_LDS16(Klo + g, &KsLo[base_row * 64]);
        }
        __syncthreads();

        f32x4 acc[2][4];
#pragma unroll
        for (int m = 0; m < 2; ++m)
#pragma unroll
            for (int n = 0; n < 4; ++n) acc[m][n] = (f32x4){0.f, 0.f, 0.f, 0.f};

#pragma unroll
        for (int ks = 0; ks < 2; ++ks) {
            short8 kh[4], kl[4];
#pragma unroll
            for (int n = 0; n < 4; ++n) {
                int row = (n << 4) + r16;
                int lc = (ks << 2) + h2;
                int phys = (row << 7) + ((lc ^ (row & 7)) << 4);
                kh[n] = *(const short8*)((const char*)KsHi + phys);
                kl[n] = *(const short8*)((const char*)KsLo + phys);
            }
#pragma unroll
            for (int m = 0; m < 2; ++m) {
                const int qm = m ? b0 : a0;
                if (j0 > qm) continue;
#pragma unroll
                for (int n = 0; n < 4; ++n) {
                    if (j0 + (n << 4) > qm + (wave << 4) + 15) continue;
                    acc[m][n] = __builtin_amdgcn_mfma_f32_16x16x32_bf16(qh[m][ks], kh[n], acc[m][n], 0, 0, 0);
                    acc[m][n] = __builtin_amdgcn_mfma_f32_16x16x32_bf16(qh[m][ks], kl[n], acc[m][n], 0, 0, 0);
                    acc[m][n] = __builtin_amdgcn_mfma_f32_16x16x32_bf16(ql[m][ks], kh[n], acc[m][n], 0, 0, 0);
                }
            }
        }

        const bool pad = (j0 + 64 > len);
#pragma unroll
        for (int m = 0; m < 2; ++m) {
            const int qm = m ? b0 : a0;
            if (j0 > qm) continue;
            const bool causal = (j0 == qm);
            if (causal || pad) {
#pragma unroll
                for (int n = 0; n < 4; ++n)
#pragma unroll
                    for (int r = 0; r < 4; ++r) {
                        int j = j0 + (n << 4) + r16;
                        int s = qm + (wave << 4) + (h2 << 2) + r;
                        if (j > s || j >= len) acc[m][n][r] = -1e30f;
                    }
                if (causal) {
#pragma unroll
                    for (int r = 0; r < 4; ++r)
                        if (r16 == (h2 << 2) + r) {
#pragma unroll
                            for (int n = 0; n < 4; ++n)
                                if (n == wave) diag[m] = acc[m][n][r];
                        }
                }
            }
#pragma unroll
            for (int r = 0; r < 4; ++r)
                sum[m][r] += __expf(acc[m][0][r]) + __expf(acc[m][1][r]) +
                             __expf(acc[m][2][r]) + __expf(acc[m][3][r]);
        }
    }

#pragma unroll
    for (int m = 0; m < 2; ++m)
#pragma unroll
        for (int r = 0; r < 4; ++r) {
            float sv = sum[m][r];
            sv += __shfl_xor(sv, 1);
            sv += __shfl_xor(sv, 2);
            sv += __shfl_xor(sv, 4);
            sv += __shfl_xor(sv, 8);
            sum[m][r] = sv;
        }

#pragma unroll
    for (int m = 0; m < 2; ++m)
#pragma unroll
        for (int r = 0; r < 4; ++r)
            if (r16 == (h2 << 2) + r)
                dbuf[(m << 6) + (wave << 4) + r16] = __expf(diag[m]) / sum[m][r];
    __syncthreads();

#pragma unroll
    for (int i = 0; i < 8; ++i) {
        int ri = i * 16 + (t >> 4);
        int c4 = (t & 15) << 2;
        int srow = (ri < 64) ? a0 + ri : b0 + ri - 64;
        float dv = dbuf[ri];
        const uint2 vv = *(const uint2*)(Vb + ((size_t)(b * S) + srow) * D + (h << 6) + c4);
        float x0 = bf2f((u16)(vv.x & 0xffffu)), x1 = bf2f((u16)(vv.x >> 16));
        float x2 = bf2f((u16)(vv.y & 0xffffu)), x3 = bf2f((u16)(vv.y >> 16));
        uint2 o;
        o.x = (unsigned)f2bf(x0 * dv) | ((unsigned)f2bf(x1 * dv) << 16);
        o.y = (unsigned)f2bf(x2 * dv) | ((unsigned)f2bf(x3 * dv) << 16);
        *(uint2*)(Wt + ((size_t)(b * S) + srow) * D + (h << 6) + c4) = o;
    }
}

extern "C" void kernel_launch(void* const* d_in, const int* in_sizes, int n_in,
                              void* d_out, int out_size, void* d_ws, size_t ws_size,
                              hipStream_t stream) {
    const float* batch = (const float*)d_in[0];
    const int* lengths = (const int*)d_in[1];
    const float* wq = (const float*)d_in[2];
    const float* bq = (const float*)d_in[3];
    const float* wk = (const float*)d_in[4];
    const float* bk = (const float*)d_in[5];
    const float* wv = (const float*)d_in[6];
    const float* bv = (const float*)d_in[7];
    const float* w0 = (const float*)d_in[8];
    const float* b0 = (const float*)d_in[9];

    const int D = in_sizes[3];            // 1024
    const int B = in_sizes[1];            // 8
    const int S = in_sizes[0] / (B * D);  // 1024
    const int H = 16;
    const int M = B * S;                  // 8192

    char* ws = (char*)d_ws;
    u16* Ab = (u16*)ws;    ws += (size_t)M * D * 2;
    u16* wcat = (u16*)ws;  ws += (size_t)3 * D * D * 2;   // [wqT; wkT; wvT]
    u16* w0T = (u16*)ws;   ws += (size_t)D * D * 2;
    u16* Qhi = (u16*)ws;   ws += (size_t)M * D * 2;
    u16* Qlo = (u16*)ws;   ws += (size_t)M * D * 2;
    u16* Khi = (u16*)ws;   ws += (size_t)M * D * 2;
    u16* Klo = (u16*)ws;   ws += (size_t)M * D * 2;
    u16* Vb = (u16*)ws;    ws += (size_t)M * D * 2;
    u16* Wtb = (u16*)ws;   ws += (size_t)M * D * 2;

    // 1. converts
    k_convert<<<(M * D / 8 + 255) / 256, 256, 0, stream>>>(batch, Ab, M * D / 8);
    dim3 tg(D / 64, D / 64);
    k_transpose<<<tg, 256, 0, stream>>>(wq, wcat, D);
    k_transpose<<<tg, 256, 0, stream>>>(wk, wcat + (size_t)D * D, D);
    k_transpose<<<tg, 256, 0, stream>>>(wv, wcat + (size_t)2 * D * D, D);
    k_transpose<<<tg, 256, 0, stream>>>(w0, w0T, D);

    // 2. fused QKV projection: M=8192, N=3072 -> (32 m)x(24 n) = 768 wgs (3/CU)
    k_gemm8<1><<<(M / 256) * (3 * D / 128), 512, 0, stream>>>(
        Ab, wcat, bq, bk, bv, Qhi, Qlo, Khi, Klo, Vb, nullptr, D, D);

    // 3. MFMA diagonal softmax + weighted = d*V
    k_scores<<<(S / 128) * H * B, 256, 0, stream>>>(Qhi, Qlo, Khi, Klo, Vb,
                                                    lengths, Wtb, S, D);

    // 4. output projection -> d_out (f32): (32 m)x(8 n) = 256 wgs (1/CU)
    k_gemm8<0><<<(M / 256) * (D / 128), 512, 0, stream>>>(
        Wtb, w0T, b0, nullptr, nullptr, nullptr, nullptr, nullptr, nullptr, nullptr,
        (float*)d_out, D, D);
}

// Round 7
// 160.698 us; speedup vs baseline: 2.8833x; 1.1248x over previous
//
#include <hip/hip_runtime.h>
#include <hip/hip_bf16.h>
#include <stdint.h>
#include <math.h>

typedef short short8 __attribute__((ext_vector_type(8)));
typedef float f32x4 __attribute__((ext_vector_type(4)));
typedef unsigned short u16;

__device__ __forceinline__ u16 f2bf(float f) {
    unsigned u = __float_as_uint(f);
    unsigned r = 0x7FFFu + ((u >> 16) & 1u);
    return (u16)((u + r) >> 16);
}
__device__ __forceinline__ float bf2f(u16 h) {
    return __uint_as_float((unsigned)h << 16);
}

#define GL_LDS16(g, l)                                                         \
    __builtin_amdgcn_global_load_lds(                                          \
        (const __attribute__((address_space(1))) void*)(g),                    \
        (__attribute__((address_space(3))) void*)(l), 16, 0, 0)

// ---------------- elementwise f32 -> bf16 convert (8 elems/thread) ----------
__global__ __launch_bounds__(256) void k_convert(const float* __restrict__ src,
                                                 u16* __restrict__ dst, int n8) {
    int i = blockIdx.x * 256 + threadIdx.x;
    if (i >= n8) return;
    const float4* s = (const float4*)src + (size_t)i * 2;
    float4 a = s[0], b = s[1];
    uint4 o;
    o.x = (unsigned)f2bf(a.x) | ((unsigned)f2bf(a.y) << 16);
    o.y = (unsigned)f2bf(a.z) | ((unsigned)f2bf(a.w) << 16);
    o.z = (unsigned)f2bf(b.x) | ((unsigned)f2bf(b.y) << 16);
    o.w = (unsigned)f2bf(b.z) | ((unsigned)f2bf(b.w) << 16);
    ((uint4*)dst)[i] = o;
}

// ---------------- transpose + convert: W[K][N] f32 -> WT[N][K] bf16 ---------
__global__ __launch_bounds__(256) void k_transpose(const float* __restrict__ W,
                                                   u16* __restrict__ WT, int Dim) {
    __shared__ float tile[64][65];
    int k0 = blockIdx.x * 64, n0 = blockIdx.y * 64;
    int t = threadIdx.x;
    int col = t & 63, rb = t >> 6;
#pragma unroll
    for (int i = 0; i < 16; ++i) {
        int r = i * 4 + rb;
        tile[r][col] = W[(size_t)(k0 + r) * Dim + n0 + col];
    }
    __syncthreads();
#pragma unroll
    for (int i = 0; i < 16; ++i) {
        int r = i * 4 + rb;
        WT[(size_t)(n0 + r) * Dim + k0 + col] = f2bf(tile[col][r]);
    }
}

// ---------------- phase-pipelined bf16 MFMA GEMM: BM=256, BN=128, BK=64 -----
// 512 threads = 8 waves (4M x 2N); per-wave output 64x64 (4m x 4n frags).
// LDS ks-major halves: A[2buf][2ks][256x32], B[2buf][2ks][128x32] (96 KiB).
// 2 phases per K-tile (one per ks): 16 MFMA + 8 ds_read_b128 + 2 stage-units.
// vmcnt(5) per phase (drain-to-5 completes exactly this phase's 3 operand
// loads); never drained to 0 in the main loop. One s_barrier per phase.
// FUSED=1 epilogue: LDS-staged coalesced writes (plane [256][128] u16 in the
// retired Asub region; 16B/lane short8 stores, 256B contiguous per 16 lanes).
template <int FUSED>
__global__ __launch_bounds__(512) void k_gemm8(
    const u16* __restrict__ A, const u16* __restrict__ BT,
    const float* __restrict__ b1, const float* __restrict__ b2,
    const float* __restrict__ b3,
    u16* __restrict__ Qh, u16* __restrict__ Ql,
    u16* __restrict__ Kh, u16* __restrict__ Kl,
    u16* __restrict__ Vb, float* __restrict__ C,
    int K, int ldo) {
    __shared__ __align__(16) u16 Asub[2][2][256 * 32];
    __shared__ __align__(16) u16 Bsub[2][2][128 * 32];

    const int wg = blockIdx.x;
    const int xcd = wg & 7, idc = wg >> 3;          // grid % 8 == 0
    const int ml = idc & 3, nbn = idc >> 2;         // 4 m-tiles per XCD chunk
    const int m0 = ((xcd << 2) + ml) << 8;          // *256
    const int n0 = nbn << 7;                        // *128
    const int t = threadIdx.x;
    const int lane = t & 63, wave = t >> 6;
    const int wr = wave >> 1, wc = wave & 1;
    const int r16 = lane & 15, kq = lane >> 4;
    const int nt = K >> 6;                          // K-tiles (16)

    // fragment LDS offsets (u16 units within one [rows][32] region), swizzled
    int offA[4], offB[4];
#pragma unroll
    for (int mi = 0; mi < 4; ++mi) {
        int row = wr * 64 + mi * 16 + r16;
        offA[mi] = row * 32 + ((kq ^ ((row >> 1) & 3)) << 3);
    }
#pragma unroll
    for (int n = 0; n < 4; ++n) {
        int row = wc * 64 + n * 16 + r16;
        offB[n] = row * 32 + ((kq ^ ((row >> 1) & 3)) << 3);
    }

    f32x4 acc[4][4];
#pragma unroll
    for (int m = 0; m < 4; ++m)
#pragma unroll
        for (int n = 0; n < 4; ++n) acc[m][n] = (f32x4){0.f, 0.f, 0.f, 0.f};

    // stage half-tile q: tile q>>2, type q&3 (0:A-ks0 1:B-ks0 2:A-ks1 3:B-ks1)
    auto stage = [&](int q) {
        const int tile = q >> 2, typ = q & 3;
        const int buf = tile & 1, ks = typ >> 1;
        const int kt = ((tile < nt ? tile : nt - 1) << 6) + (ks << 5);
        if (!(typ & 1)) {  // A half: 16 KB = 2 loads/thread
#pragma unroll
            for (int r = 0; r < 2; ++r) {
                int li = (r << 9) + t;
                int row = li >> 2;
                int kk = ((li & 3) ^ ((row >> 1) & 3)) << 3;
                GL_LDS16(A + (size_t)(m0 + row) * K + kt + kk,
                         &Asub[buf][ks][(li & ~63) << 3]);
            }
        } else {           // B half: 8 KB = 1 load/thread
            int li = t;
            int row = li >> 2;
            int kk = ((li & 3) ^ ((row >> 1) & 3)) << 3;
            GL_LDS16(BT + (size_t)(n0 + row) * K + kt + kk,
                     &Bsub[buf][ks][(li & ~63) << 3]);
        }
    };

    // prologue: HT0..4 (tile0 complete + tile1 A-ks0) -> 8 loads/thread
    for (int q = 0; q < 5; ++q) stage(q);

    for (int tile = 0; tile < nt; ++tile) {
        const int buf = tile & 1;
#pragma unroll
        for (int ks = 0; ks < 2; ++ks) {
            asm volatile("s_waitcnt vmcnt(5)" ::: "memory");
            __builtin_amdgcn_sched_barrier(0);
            __builtin_amdgcn_s_barrier();
            __builtin_amdgcn_sched_barrier(0);
            const u16* Ar = Asub[buf][ks];
            const u16* Br = Bsub[buf][ks];
            short8 a[4], bfr[4];
#pragma unroll
            for (int mi = 0; mi < 4; ++mi)
                a[mi] = *(const short8*)(Ar + offA[mi]);
#pragma unroll
            for (int n = 0; n < 4; ++n)
                bfr[n] = *(const short8*)(Br + offB[n]);
            stage(tile * 4 + 2 * ks + 5);
            stage(tile * 4 + 2 * ks + 6);
            asm volatile("s_waitcnt lgkmcnt(0)" ::: "memory");
            __builtin_amdgcn_sched_barrier(0);
            __builtin_amdgcn_s_setprio(1);
#pragma unroll
            for (int mi = 0; mi < 4; ++mi)
#pragma unroll
                for (int n = 0; n < 4; ++n)
                    acc[mi][n] = __builtin_amdgcn_mfma_f32_16x16x32_bf16(
                        a[mi], bfr[n], acc[mi][n], 0, 0, 0);
            __builtin_amdgcn_s_setprio(0);
            __builtin_amdgcn_sched_barrier(0);
        }
    }
    asm volatile("s_waitcnt vmcnt(0)" ::: "memory");

    if (FUSED) {
        const int seg = n0 >> 10;
        const float* bias = (seg == 0) ? b1 : (seg == 1) ? b2 : b3;
        u16* oh = (seg == 0) ? Qh : (seg == 1) ? Kh : Vb;
        u16* ol = (seg == 0) ? Ql : Kl;  // unused when seg==2
        const int nc0 = n0 & 1023;
        const int nplanes = (seg < 2) ? 2 : 1;
        u16* lds = &Asub[0][0][0];       // retired pipeline LDS: [256][128] u16
        for (int p = 0; p < nplanes; ++p) {
            __syncthreads();             // LDS free / previous plane drained
#pragma unroll
            for (int n = 0; n < 4; ++n) {
                int col = wc * 64 + n * 16 + r16;
                float bvv = bias[nc0 + col];
#pragma unroll
                for (int mi = 0; mi < 4; ++mi) {
                    int row = wr * 64 + mi * 16 + kq * 4;
#pragma unroll
                    for (int j = 0; j < 4; ++j) {
                        float val = acc[mi][n][j] + bvv;
                        u16 hi = f2bf(val);
                        u16 w = p ? f2bf(val - bf2f(hi)) : hi;
                        lds[(row + j) * 128 + col] = w;
                    }
                }
            }
            __syncthreads();
            u16* dst = p ? ol : oh;
#pragma unroll
            for (int i = 0; i < 8; ++i) {
                int li = (i << 9) + t;          // 0..4095
                int row = li >> 4, ch = li & 15;
                short8 v = *(const short8*)&lds[row * 128 + ch * 8];
                *(short8*)(dst + (size_t)(m0 + row) * ldo + nc0 + ch * 8) = v;
            }
        }
    } else {
#pragma unroll
        for (int n = 0; n < 4; ++n) {
            int col = n0 + wc * 64 + n * 16 + r16;
            float bvv = b1[col];
#pragma unroll
            for (int mi = 0; mi < 4; ++mi) {
                int row = m0 + wr * 64 + mi * 16 + kq * 4;
#pragma unroll
                for (int j = 0; j < 4; ++j)
                    C[(size_t)(row + j) * ldo + col] = acc[mi][n][j] + bvv;
            }
        }
    }
}

// ---------------- MFMA diagonal-softmax + weighted = d*V --------------------
// 1024 blocks (4/CU), 256 threads = 4 waves. Block bx pairs 64-row chunk bx
// with chunk (15-bx) -> uniform work. Same-(b,h) blocks share an XCD.
__global__ __launch_bounds__(256, 2) void k_scores(
    const u16* __restrict__ Qhi, const u16* __restrict__ Qlo,
    const u16* __restrict__ Khi, const u16* __restrict__ Klo,
    const u16* __restrict__ Vb, const int* __restrict__ lengths,
    u16* __restrict__ Wt, int S, int D) {
    __shared__ __align__(16) u16 KsHi[64 * 64];
    __shared__ __align__(16) u16 KsLo[64 * 64];
    __shared__ float dbuf[128];

    const int wg = blockIdx.x;
    const int xcd = wg & 7, idc = wg >> 3;
    const int bh = (xcd << 4) + (idc >> 3);    // 16 (b,h) per XCD
    const int bx = idc & 7;
    const int b = bh >> 4, h = bh & 15;
    const int nchunk = S >> 6;                 // 16
    const int a0 = bx << 6;
    const int b0 = (nchunk - 1 - bx) << 6;

    const int t = threadIdx.x;
    const int lane = t & 63, wave = t >> 6;
    const int r16 = lane & 15, h2 = lane >> 4;
    const int len = lengths[b];

    short8 qh[2][2], ql[2][2];
#pragma unroll
    for (int m = 0; m < 2; ++m) {
        const int qm = m ? b0 : a0;
        const int row = qm + (wave << 4) + r16;
#pragma unroll
        for (int ks = 0; ks < 2; ++ks) {
            size_t off = ((size_t)(b * S) + row) * D + (h << 6) + (ks << 5) + (h2 << 3);
            qh[m][ks] = *(const short8*)(Qhi + off);
            ql[m][ks] = *(const short8*)(Qlo + off);
        }
    }

    float sum[2][4];
    float diag[2] = {-1e30f, -1e30f};
#pragma unroll
    for (int m = 0; m < 2; ++m)
#pragma unroll
        for (int r = 0; r < 4; ++r) sum[m][r] = 0.f;

    const int jmax = min(b0 + 63, len - 1);
    for (int j0 = 0; j0 <= jmax; j0 += 64) {
        __syncthreads();
#pragma unroll
        for (int p = 0; p < 2; ++p) {
            const int base_row = p * 32 + wave * 8;       // wave-uniform
            const int row = base_row + (lane >> 3);
            const int lc = (lane & 7) ^ (row & 7);
            size_t g = ((size_t)(b * S) + j0 + row) * D + (h << 6) + (lc << 3);
            GL_LDS16(Khi + g, &KsHi[base_row * 64]);
            GL_LDS16(Klo + g, &KsLo[base_row * 64]);
        }
        __syncthreads();

        f32x4 acc[2][4];
#pragma unroll
        for (int m = 0; m < 2; ++m)
#pragma unroll
            for (int n = 0; n < 4; ++n) acc[m][n] = (f32x4){0.f, 0.f, 0.f, 0.f};

#pragma unroll
        for (int ks = 0; ks < 2; ++ks) {
            short8 kh[4], kl[4];
#pragma unroll
            for (int n = 0; n < 4; ++n) {
                int row = (n << 4) + r16;
                int lc = (ks << 2) + h2;
                int phys = (row << 7) + ((lc ^ (row & 7)) << 4);
                kh[n] = *(const short8*)((const char*)KsHi + phys);
                kl[n] = *(const short8*)((const char*)KsLo + phys);
            }
#pragma unroll
            for (int m = 0; m < 2; ++m) {
                const int qm = m ? b0 : a0;
                if (j0 > qm) continue;
#pragma unroll
                for (int n = 0; n < 4; ++n) {
                    if (j0 + (n << 4) > qm + (wave << 4) + 15) continue;
                    acc[m][n] = __builtin_amdgcn_mfma_f32_16x16x32_bf16(qh[m][ks], kh[n], acc[m][n], 0, 0, 0);
                    acc[m][n] = __builtin_amdgcn_mfma_f32_16x16x32_bf16(qh[m][ks], kl[n], acc[m][n], 0, 0, 0);
                    acc[m][n] = __builtin_amdgcn_mfma_f32_16x16x32_bf16(ql[m][ks], kh[n], acc[m][n], 0, 0, 0);
                }
            }
        }

        const bool pad = (j0 + 64 > len);
#pragma unroll
        for (int m = 0; m < 2; ++m) {
            const int qm = m ? b0 : a0;
            if (j0 > qm) continue;
            const bool causal = (j0 == qm);
            if (causal || pad) {
#pragma unroll
                for (int n = 0; n < 4; ++n)
#pragma unroll
                    for (int r = 0; r < 4; ++r) {
                        int j = j0 + (n << 4) + r16;
                        int s = qm + (wave << 4) + (h2 << 2) + r;
                        if (j > s || j >= len) acc[m][n][r] = -1e30f;
                    }
                if (causal) {
#pragma unroll
                    for (int r = 0; r < 4; ++r)
                        if (r16 == (h2 << 2) + r) {
#pragma unroll
                            for (int n = 0; n < 4; ++n)
                                if (n == wave) diag[m] = acc[m][n][r];
                        }
                }
            }
#pragma unroll
            for (int r = 0; r < 4; ++r)
                sum[m][r] += __expf(acc[m][0][r]) + __expf(acc[m][1][r]) +
                             __expf(acc[m][2][r]) + __expf(acc[m][3][r]);
        }
    }

#pragma unroll
    for (int m = 0; m < 2; ++m)
#pragma unroll
        for (int r = 0; r < 4; ++r) {
            float sv = sum[m][r];
            sv += __shfl_xor(sv, 1);
            sv += __shfl_xor(sv, 2);
            sv += __shfl_xor(sv, 4);
            sv += __shfl_xor(sv, 8);
            sum[m][r] = sv;
        }

#pragma unroll
    for (int m = 0; m < 2; ++m)
#pragma unroll
        for (int r = 0; r < 4; ++r)
            if (r16 == (h2 << 2) + r)
                dbuf[(m << 6) + (wave << 4) + r16] = __expf(diag[m]) / sum[m][r];
    __syncthreads();

#pragma unroll
    for (int i = 0; i < 8; ++i) {
        int ri = i * 16 + (t >> 4);
        int c4 = (t & 15) << 2;
        int srow = (ri < 64) ? a0 + ri : b0 + ri - 64;
        float dv = dbuf[ri];
        const uint2 vv = *(const uint2*)(Vb + ((size_t)(b * S) + srow) * D + (h << 6) + c4);
        float x0 = bf2f((u16)(vv.x & 0xffffu)), x1 = bf2f((u16)(vv.x >> 16));
        float x2 = bf2f((u16)(vv.y & 0xffffu)), x3 = bf2f((u16)(vv.y >> 16));
        uint2 o;
        o.x = (unsigned)f2bf(x0 * dv) | ((unsigned)f2bf(x1 * dv) << 16);
        o.y = (unsigned)f2bf(x2 * dv) | ((unsigned)f2bf(x3 * dv) << 16);
        *(uint2*)(Wt + ((size_t)(b * S) + srow) * D + (h << 6) + c4) = o;
    }
}

extern "C" void kernel_launch(void* const* d_in, const int* in_sizes, int n_in,
                              void* d_out, int out_size, void* d_ws, size_t ws_size,
                              hipStream_t stream) {
    const float* batch = (const float*)d_in[0];
    const int* lengths = (const int*)d_in[1];
    const float* wq = (const float*)d_in[2];
    const float* bq = (const float*)d_in[3];
    const float* wk = (const float*)d_in[4];
    const float* bk = (const float*)d_in[5];
    const float* wv = (const float*)d_in[6];
    const float* bv = (const float*)d_in[7];
    const float* w0 = (const float*)d_in[8];
    const float* b0 = (const float*)d_in[9];

    const int D = in_sizes[3];            // 1024
    const int B = in_sizes[1];            // 8
    const int S = in_sizes[0] / (B * D);  // 1024
    const int H = 16;
    const int M = B * S;                  // 8192

    char* ws = (char*)d_ws;
    u16* Ab = (u16*)ws;    ws += (size_t)M * D * 2;
    u16* wcat = (u16*)ws;  ws += (size_t)3 * D * D * 2;   // [wqT; wkT; wvT]
    u16* w0T = (u16*)ws;   ws += (size_t)D * D * 2;
    u16* Qhi = (u16*)ws;   ws += (size_t)M * D * 2;
    u16* Qlo = (u16*)ws;   ws += (size_t)M * D * 2;
    u16* Khi = (u16*)ws;   ws += (size_t)M * D * 2;
    u16* Klo = (u16*)ws;   ws += (size_t)M * D * 2;
    u16* Vb = (u16*)ws;    ws += (size_t)M * D * 2;
    u16* Wtb = (u16*)ws;   ws += (size_t)M * D * 2;

    // 1. converts
    k_convert<<<(M * D / 8 + 255) / 256, 256, 0, stream>>>(batch, Ab, M * D / 8);
    dim3 tg(D / 64, D / 64);
    k_transpose<<<tg, 256, 0, stream>>>(wq, wcat, D);
    k_transpose<<<tg, 256, 0, stream>>>(wk, wcat + (size_t)D * D, D);
    k_transpose<<<tg, 256, 0, stream>>>(wv, wcat + (size_t)2 * D * D, D);
    k_transpose<<<tg, 256, 0, stream>>>(w0, w0T, D);

    // 2. fused QKV projection: M=8192, N=3072 -> (32 m)x(24 n) = 768 wgs (3/CU)
    k_gemm8<1><<<(M / 256) * (3 * D / 128), 512, 0, stream>>>(
        Ab, wcat, bq, bk, bv, Qhi, Qlo, Khi, Klo, Vb, nullptr, D, D);

    // 3. MFMA diagonal softmax + weighted = d*V
    k_scores<<<(S / 128) * H * B, 256, 0, stream>>>(Qhi, Qlo, Khi, Klo, Vb,
                                                    lengths, Wtb, S, D);

    // 4. output projection -> d_out (f32): (32 m)x(8 n) = 256 wgs (1/CU)
    k_gemm8<0><<<(M / 256) * (D / 128), 512, 0, stream>>>(
        Wtb, w0T, b0, nullptr, nullptr, nullptr, nullptr, nullptr, nullptr, nullptr,
        (float*)d_out, D, D);
}

// Round 8
// 159.216 us; speedup vs baseline: 2.9101x; 1.0093x over previous
//
#include <hip/hip_runtime.h>
#include <hip/hip_bf16.h>
#include <stdint.h>
#include <math.h>

typedef short short8 __attribute__((ext_vector_type(8)));
typedef float f32x4 __attribute__((ext_vector_type(4)));
typedef unsigned short u16;

__device__ __forceinline__ u16 f2bf(float f) {
    unsigned u = __float_as_uint(f);
    unsigned r = 0x7FFFu + ((u >> 16) & 1u);
    return (u16)((u + r) >> 16);
}
__device__ __forceinline__ float bf2f(u16 h) {
    return __uint_as_float((unsigned)h << 16);
}

#define GL_LDS16(g, l)                                                         \
    __builtin_amdgcn_global_load_lds(                                          \
        (const __attribute__((address_space(1))) void*)(g),                    \
        (__attribute__((address_space(3))) void*)(l), 16, 0, 0)

// ---------------- elementwise f32 -> bf16 convert (8 elems/thread) ----------
__global__ __launch_bounds__(256) void k_convert(const float* __restrict__ src,
                                                 u16* __restrict__ dst, int n8) {
    int i = blockIdx.x * 256 + threadIdx.x;
    if (i >= n8) return;
    const float4* s = (const float4*)src + (size_t)i * 2;
    float4 a = s[0], b = s[1];
    uint4 o;
    o.x = (unsigned)f2bf(a.x) | ((unsigned)f2bf(a.y) << 16);
    o.y = (unsigned)f2bf(a.z) | ((unsigned)f2bf(a.w) << 16);
    o.z = (unsigned)f2bf(b.x) | ((unsigned)f2bf(b.y) << 16);
    o.w = (unsigned)f2bf(b.z) | ((unsigned)f2bf(b.w) << 16);
    ((uint4*)dst)[i] = o;
}

// ---------------- transpose + convert: W[K][N] f32 -> WT[N][K] bf16 ---------
__global__ __launch_bounds__(256) void k_transpose(const float* __restrict__ W,
                                                   u16* __restrict__ WT, int Dim) {
    __shared__ float tile[64][65];
    int k0 = blockIdx.x * 64, n0 = blockIdx.y * 64;
    int t = threadIdx.x;
    int col = t & 63, rb = t >> 6;
#pragma unroll
    for (int i = 0; i < 16; ++i) {
        int r = i * 4 + rb;
        tile[r][col] = W[(size_t)(k0 + r) * Dim + n0 + col];
    }
    __syncthreads();
#pragma unroll
    for (int i = 0; i < 16; ++i) {
        int r = i * 4 + rb;
        WT[(size_t)(n0 + r) * Dim + k0 + col] = f2bf(tile[col][r]);
    }
}

// ---------------- phase-pipelined bf16 MFMA GEMM: BM=256, BN=128, BK=64 -----
// 512 threads = 8 waves (4M x 2N); per-wave output 64x64 (4m x 4n frags).
// LDS: 3-buffer rotation (WAR-free staging), A[3][2ks][256x32] + B[3][2ks]
// [128x32] = 144 KiB. ONE barrier per K-tile: read all 16 frags, lgkmcnt(8)
// -> MFMA ks0 overlaps ks1 read completion, lgkmcnt(0) -> MFMA ks1. Whole
// next+2 tile (6 loads) staged at tile-top, hidden under both MFMA clusters.
// vmcnt(6) steady state (tile t+1's 6 loads in flight), vmcnt(0) last tile.
// FUSED=1 epilogue: LDS-staged coalesced stores (plane [256][128] u16).
template <int FUSED>
__global__ __launch_bounds__(512) void k_gemm8(
    const u16* __restrict__ A, const u16* __restrict__ BT,
    const float* __restrict__ b1, const float* __restrict__ b2,
    const float* __restrict__ b3,
    u16* __restrict__ Qh, u16* __restrict__ Ql,
    u16* __restrict__ Kh, u16* __restrict__ Kl,
    u16* __restrict__ Vb, float* __restrict__ C,
    int K, int ldo) {
    __shared__ __align__(16) u16 ldsbuf[73728];   // 144 KiB

    const int wg = blockIdx.x;
    const int xcd = wg & 7, idc = wg >> 3;          // grid % 8 == 0
    const int ml = idc & 3, nbn = idc >> 2;         // 4 m-tiles per XCD chunk
    const int m0 = ((xcd << 2) + ml) << 8;          // *256
    const int n0 = nbn << 7;                        // *128
    const int t = threadIdx.x;
    const int lane = t & 63, wave = t >> 6;
    const int wr = wave >> 1, wc = wave & 1;
    const int r16 = lane & 15, kq = lane >> 4;
    const int nt = K >> 6;                          // K-tiles (16)

    // fragment LDS offsets (u16 units within one [rows][32] half), swizzled
    int offA[4], offB[4];
#pragma unroll
    for (int mi = 0; mi < 4; ++mi) {
        int row = wr * 64 + mi * 16 + r16;
        offA[mi] = row * 32 + ((kq ^ ((row >> 1) & 3)) << 3);
    }
#pragma unroll
    for (int n = 0; n < 4; ++n) {
        int row = wc * 64 + n * 16 + r16;
        offB[n] = row * 32 + ((kq ^ ((row >> 1) & 3)) << 3);
    }

    f32x4 acc[4][4];
#pragma unroll
    for (int m = 0; m < 4; ++m)
#pragma unroll
        for (int n = 0; n < 4; ++n) acc[m][n] = (f32x4){0.f, 0.f, 0.f, 0.f};

    // stage one whole K-tile (6 loads: A-ks0 x2, B-ks0, A-ks1 x2, B-ks1)
    auto stage_tile = [&](int tile, int buf) {
        const int kt = tile << 6;
        u16* Abase = ldsbuf + buf * 16384;
        u16* Bbase = ldsbuf + 49152 + buf * 8192;
#pragma unroll
        for (int ks = 0; ks < 2; ++ks) {
#pragma unroll
            for (int r = 0; r < 2; ++r) {
                int li = (r << 9) + t;
                int row = li >> 2;
                int kk = ((li & 3) ^ ((row >> 1) & 3)) << 3;
                GL_LDS16(A + (size_t)(m0 + row) * K + kt + (ks << 5) + kk,
                         Abase + (ks << 13) + ((li & ~63) << 3));
            }
            {
                int li = t;
                int row = li >> 2;
                int kk = ((li & 3) ^ ((row >> 1) & 3)) << 3;
                GL_LDS16(BT + (size_t)(n0 + row) * K + kt + (ks << 5) + kk,
                         Bbase + (ks << 12) + ((li & ~63) << 3));
            }
        }
    };

    // prologue: tiles 0 and 1 in flight (12 loads)
    stage_tile(0, 0);
    stage_tile(1, 1);

    for (int tile = 0; tile < nt; ++tile) {
        const int buf = tile % 3;
        if (tile + 1 < nt)
            asm volatile("s_waitcnt vmcnt(6)" ::: "memory");
        else
            asm volatile("s_waitcnt vmcnt(0)" ::: "memory");
        __builtin_amdgcn_sched_barrier(0);
        __builtin_amdgcn_s_barrier();
        __builtin_amdgcn_sched_barrier(0);
        if (tile + 2 < nt) stage_tile(tile + 2, (tile + 2) % 3);

        const u16* Ab0 = ldsbuf + buf * 16384;
        const u16* Bb0 = ldsbuf + 49152 + buf * 8192;
        short8 a0[4], b0f[4], a1[4], b1f[4];
#pragma unroll
        for (int mi = 0; mi < 4; ++mi) a0[mi] = *(const short8*)(Ab0 + offA[mi]);
#pragma unroll
        for (int n = 0; n < 4; ++n) b0f[n] = *(const short8*)(Bb0 + offB[n]);
        __builtin_amdgcn_sched_barrier(0);   // pin: ks0 reads issued first
#pragma unroll
        for (int mi = 0; mi < 4; ++mi) a1[mi] = *(const short8*)(Ab0 + 8192 + offA[mi]);
#pragma unroll
        for (int n = 0; n < 4; ++n) b1f[n] = *(const short8*)(Bb0 + 4096 + offB[n]);

        asm volatile("s_waitcnt lgkmcnt(8)" ::: "memory");
        __builtin_amdgcn_sched_barrier(0);
        __builtin_amdgcn_s_setprio(1);
#pragma unroll
        for (int mi = 0; mi < 4; ++mi)
#pragma unroll
            for (int n = 0; n < 4; ++n)
                acc[mi][n] = __builtin_amdgcn_mfma_f32_16x16x32_bf16(
                    a0[mi], b0f[n], acc[mi][n], 0, 0, 0);
        __builtin_amdgcn_s_setprio(0);
        __builtin_amdgcn_sched_barrier(0);
        asm volatile("s_waitcnt lgkmcnt(0)" ::: "memory");
        __builtin_amdgcn_sched_barrier(0);
        __builtin_amdgcn_s_setprio(1);
#pragma unroll
        for (int mi = 0; mi < 4; ++mi)
#pragma unroll
            for (int n = 0; n < 4; ++n)
                acc[mi][n] = __builtin_amdgcn_mfma_f32_16x16x32_bf16(
                    a1[mi], b1f[n], acc[mi][n], 0, 0, 0);
        __builtin_amdgcn_s_setprio(0);
        __builtin_amdgcn_sched_barrier(0);
    }
    asm volatile("s_waitcnt vmcnt(0)" ::: "memory");

    if (FUSED) {
        const int seg = n0 >> 10;
        const float* bias = (seg == 0) ? b1 : (seg == 1) ? b2 : b3;
        u16* oh = (seg == 0) ? Qh : (seg == 1) ? Kh : Vb;
        u16* ol = (seg == 0) ? Ql : Kl;  // unused when seg==2
        const int nc0 = n0 & 1023;
        const int nplanes = (seg < 2) ? 2 : 1;
        u16* lds = ldsbuf;               // retired pipeline LDS: [256][128] u16
        for (int p = 0; p < nplanes; ++p) {
            __syncthreads();             // LDS free / previous plane drained
#pragma unroll
            for (int n = 0; n < 4; ++n) {
                int col = wc * 64 + n * 16 + r16;
                float bvv = bias[nc0 + col];
#pragma unroll
                for (int mi = 0; mi < 4; ++mi) {
                    int row = wr * 64 + mi * 16 + kq * 4;
#pragma unroll
                    for (int j = 0; j < 4; ++j) {
                        float val = acc[mi][n][j] + bvv;
                        u16 hi = f2bf(val);
                        u16 w = p ? f2bf(val - bf2f(hi)) : hi;
                        lds[(row + j) * 128 + col] = w;
                    }
                }
            }
            __syncthreads();
            u16* dst = p ? ol : oh;
#pragma unroll
            for (int i = 0; i < 8; ++i) {
                int li = (i << 9) + t;          // 0..4095
                int row = li >> 4, ch = li & 15;
                short8 v = *(const short8*)&lds[row * 128 + ch * 8];
                *(short8*)(dst + (size_t)(m0 + row) * ldo + nc0 + ch * 8) = v;
            }
        }
    } else {
#pragma unroll
        for (int n = 0; n < 4; ++n) {
            int col = n0 + wc * 64 + n * 16 + r16;
            float bvv = b1[col];
#pragma unroll
            for (int mi = 0; mi < 4; ++mi) {
                int row = m0 + wr * 64 + mi * 16 + kq * 4;
#pragma unroll
                for (int j = 0; j < 4; ++j)
                    C[(size_t)(row + j) * ldo + col] = acc[mi][n][j] + bvv;
            }
        }
    }
}

// ---------------- MFMA diagonal-softmax + weighted = d*V --------------------
// 1024 blocks (4/CU), 256 threads = 4 waves. Block bx pairs 64-row chunk bx
// with chunk (15-bx) -> uniform work. Same-(b,h) blocks share an XCD.
__global__ __launch_bounds__(256, 2) void k_scores(
    const u16* __restrict__ Qhi, const u16* __restrict__ Qlo,
    const u16* __restrict__ Khi, const u16* __restrict__ Klo,
    const u16* __restrict__ Vb, const int* __restrict__ lengths,
    u16* __restrict__ Wt, int S, int D) {
    __shared__ __align__(16) u16 KsHi[64 * 64];
    __shared__ __align__(16) u16 KsLo[64 * 64];
    __shared__ float dbuf[128];

    const int wg = blockIdx.x;
    const int xcd = wg & 7, idc = wg >> 3;
    const int bh = (xcd << 4) + (idc >> 3);    // 16 (b,h) per XCD
    const int bx = idc & 7;
    const int b = bh >> 4, h = bh & 15;
    const int nchunk = S >> 6;                 // 16
    const int a0 = bx << 6;
    const int b0 = (nchunk - 1 - bx) << 6;

    const int t = threadIdx.x;
    const int lane = t & 63, wave = t >> 6;
    const int r16 = lane & 15, h2 = lane >> 4;
    const int len = lengths[b];

    short8 qh[2][2], ql[2][2];
#pragma unroll
    for (int m = 0; m < 2; ++m) {
        const int qm = m ? b0 : a0;
        const int row = qm + (wave << 4) + r16;
#pragma unroll
        for (int ks = 0; ks < 2; ++ks) {
            size_t off = ((size_t)(b * S) + row) * D + (h << 6) + (ks << 5) + (h2 << 3);
            qh[m][ks] = *(const short8*)(Qhi + off);
            ql[m][ks] = *(const short8*)(Qlo + off);
        }
    }

    float sum[2][4];
    float diag[2] = {-1e30f, -1e30f};
#pragma unroll
    for (int m = 0; m < 2; ++m)
#pragma unroll
        for (int r = 0; r < 4; ++r) sum[m][r] = 0.f;

    const int jmax = min(b0 + 63, len - 1);
    for (int j0 = 0; j0 <= jmax; j0 += 64) {
        __syncthreads();
#pragma unroll
        for (int p = 0; p < 2; ++p) {
            const int base_row = p * 32 + wave * 8;       // wave-uniform
            const int row = base_row + (lane >> 3);
            const int lc = (lane & 7) ^ (row & 7);
            size_t g = ((size_t)(b * S) + j0 + row) * D + (h << 6) + (lc << 3);
            GL_LDS16(Khi + g, &KsHi[base_row * 64]);
            GL_LDS16(Klo + g, &KsLo[base_row * 64]);
        }
        __syncthreads();

        f32x4 acc[2][4];
#pragma unroll
        for (int m = 0; m < 2; ++m)
#pragma unroll
            for (int n = 0; n < 4; ++n) acc[m][n] = (f32x4){0.f, 0.f, 0.f, 0.f};

#pragma unroll
        for (int ks = 0; ks < 2; ++ks) {
            short8 kh[4], kl[4];
#pragma unroll
            for (int n = 0; n < 4; ++n) {
                int row = (n << 4) + r16;
                int lc = (ks << 2) + h2;
                int phys = (row << 7) + ((lc ^ (row & 7)) << 4);
                kh[n] = *(const short8*)((const char*)KsHi + phys);
                kl[n] = *(const short8*)((const char*)KsLo + phys);
            }
#pragma unroll
            for (int m = 0; m < 2; ++m) {
                const int qm = m ? b0 : a0;
                if (j0 > qm) continue;
#pragma unroll
                for (int n = 0; n < 4; ++n) {
                    if (j0 + (n << 4) > qm + (wave << 4) + 15) continue;
                    acc[m][n] = __builtin_amdgcn_mfma_f32_16x16x32_bf16(qh[m][ks], kh[n], acc[m][n], 0, 0, 0);
                    acc[m][n] = __builtin_amdgcn_mfma_f32_16x16x32_bf16(qh[m][ks], kl[n], acc[m][n], 0, 0, 0);
                    acc[m][n] = __builtin_amdgcn_mfma_f32_16x16x32_bf16(ql[m][ks], kh[n], acc[m][n], 0, 0, 0);
                }
            }
        }

        const bool pad = (j0 + 64 > len);
#pragma unroll
        for (int m = 0; m < 2; ++m) {
            const int qm = m ? b0 : a0;
            if (j0 > qm) continue;
            const bool causal = (j0 == qm);
            if (causal || pad) {
#pragma unroll
                for (int n = 0; n < 4; ++n)
#pragma unroll
                    for (int r = 0; r < 4; ++r) {
                        int j = j0 + (n << 4) + r16;
                        int s = qm + (wave << 4) + (h2 << 2) + r;
                        if (j > s || j >= len) acc[m][n][r] = -1e30f;
                    }
                if (causal) {
#pragma unroll
                    for (int r = 0; r < 4; ++r)
                        if (r16 == (h2 << 2) + r) {
#pragma unroll
                            for (int n = 0; n < 4; ++n)
                                if (n == wave) diag[m] = acc[m][n][r];
                        }
                }
            }
#pragma unroll
            for (int r = 0; r < 4; ++r)
                sum[m][r] += __expf(acc[m][0][r]) + __expf(acc[m][1][r]) +
                             __expf(acc[m][2][r]) + __expf(acc[m][3][r]);
        }
    }

#pragma unroll
    for (int m = 0; m < 2; ++m)
#pragma unroll
        for (int r = 0; r < 4; ++r) {
            float sv = sum[m][r];
            sv += __shfl_xor(sv, 1);
            sv += __shfl_xor(sv, 2);
            sv += __shfl_xor(sv, 4);
            sv += __shfl_xor(sv, 8);
            sum[m][r] = sv;
        }

#pragma unroll
    for (int m = 0; m < 2; ++m)
#pragma unroll
        for (int r = 0; r < 4; ++r)
            if (r16 == (h2 << 2) + r)
                dbuf[(m << 6) + (wave << 4) + r16] = __expf(diag[m]) / sum[m][r];
    __syncthreads();

#pragma unroll
    for (int i = 0; i < 8; ++i) {
        int ri = i * 16 + (t >> 4);
        int c4 = (t & 15) << 2;
        int srow = (ri < 64) ? a0 + ri : b0 + ri - 64;
        float dv = dbuf[ri];
        const uint2 vv = *(const uint2*)(Vb + ((size_t)(b * S) + srow) * D + (h << 6) + c4);
        float x0 = bf2f((u16)(vv.x & 0xffffu)), x1 = bf2f((u16)(vv.x >> 16));
        float x2 = bf2f((u16)(vv.y & 0xffffu)), x3 = bf2f((u16)(vv.y >> 16));
        uint2 o;
        o.x = (unsigned)f2bf(x0 * dv) | ((unsigned)f2bf(x1 * dv) << 16);
        o.y = (unsigned)f2bf(x2 * dv) | ((unsigned)f2bf(x3 * dv) << 16);
        *(uint2*)(Wt + ((size_t)(b * S) + srow) * D + (h << 6) + c4) = o;
    }
}

extern "C" void kernel_launch(void* const* d_in, const int* in_sizes, int n_in,
                              void* d_out, int out_size, void* d_ws, size_t ws_size,
                              hipStream_t stream) {
    const float* batch = (const float*)d_in[0];
    const int* lengths = (const int*)d_in[1];
    const float* wq = (const float*)d_in[2];
    const float* bq = (const float*)d_in[3];
    const float* wk = (const float*)d_in[4];
    const float* bk = (const float*)d_in[5];
    const float* wv = (const float*)d_in[6];
    const float* bv = (const float*)d_in[7];
    const float* w0 = (const float*)d_in[8];
    const float* b0 = (const float*)d_in[9];

    const int D = in_sizes[3];            // 1024
    const int B = in_sizes[1];            // 8
    const int S = in_sizes[0] / (B * D);  // 1024
    const int H = 16;
    const int M = B * S;                  // 8192

    char* ws = (char*)d_ws;
    u16* Ab = (u16*)ws;    ws += (size_t)M * D * 2;
    u16* wcat = (u16*)ws;  ws += (size_t)3 * D * D * 2;   // [wqT; wkT; wvT]
    u16* w0T = (u16*)ws;   ws += (size_t)D * D * 2;
    u16* Qhi = (u16*)ws;   ws += (size_t)M * D * 2;
    u16* Qlo = (u16*)ws;   ws += (size_t)M * D * 2;
    u16* Khi = (u16*)ws;   ws += (size_t)M * D * 2;
    u16* Klo = (u16*)ws;   ws += (size_t)M * D * 2;
    u16* Vb = (u16*)ws;    ws += (size_t)M * D * 2;
    u16* Wtb = (u16*)ws;   ws += (size_t)M * D * 2;

    // 1. converts
    k_convert<<<(M * D / 8 + 255) / 256, 256, 0, stream>>>(batch, Ab, M * D / 8);
    dim3 tg(D / 64, D / 64);
    k_transpose<<<tg, 256, 0, stream>>>(wq, wcat, D);
    k_transpose<<<tg, 256, 0, stream>>>(wk, wcat + (size_t)D * D, D);
    k_transpose<<<tg, 256, 0, stream>>>(wv, wcat + (size_t)2 * D * D, D);
    k_transpose<<<tg, 256, 0, stream>>>(w0, w0T, D);

    // 2. fused QKV projection: M=8192, N=3072 -> (32 m)x(24 n) = 768 wgs (3/CU)
    k_gemm8<1><<<(M / 256) * (3 * D / 128), 512, 0, stream>>>(
        Ab, wcat, bq, bk, bv, Qhi, Qlo, Khi, Klo, Vb, nullptr, D, D);

    // 3. MFMA diagonal softmax + weighted = d*V
    k_scores<<<(S / 128) * H * B, 256, 0, stream>>>(Qhi, Qlo, Khi, Klo, Vb,
                                                    lengths, Wtb, S, D);

    // 4. output projection -> d_out (f32): (32 m)x(8 n) = 256 wgs (1/CU)
    k_gemm8<0><<<(M / 256) * (D / 128), 512, 0, stream>>>(
        Wtb, w0T, b0, nullptr, nullptr, nullptr, nullptr, nullptr, nullptr, nullptr,
        (float*)d_out, D, D);
}